// Round 7
// baseline (1643.736 us; speedup 1.0000x reference)
//
#include <hip/hip_runtime.h>

#define T_LEN 2048
#define E_DIM 1024
#define H_N 16
#define G_N 4
#define D_H 64
#define F_DIM 4096
#define V_SZ 32000
#define L_N 4

typedef __attribute__((ext_vector_type(8))) __bf16 bf16x8;
typedef __attribute__((ext_vector_type(4))) float f32x4;

__device__ __forceinline__ unsigned short f2bf(float f){
  unsigned int u = __float_as_uint(f);
  unsigned int r = (u + 0x7FFFu + ((u >> 16) & 1u)) >> 16;
  return (unsigned short)r;
}

__device__ __forceinline__ f32x4 mfma16(bf16x8 a, bf16x8 b, f32x4 c){
  return __builtin_amdgcn_mfma_f32_16x16x32_bf16(a, b, c, 0, 0, 0);
}

__device__ __forceinline__ void gl16(const void* g, void* l){
  __builtin_amdgcn_global_load_lds((const __attribute__((address_space(1))) void*)g,
                                   (__attribute__((address_space(3))) void*)l, 16, 0, 0);
}

#define SBAR() __builtin_amdgcn_s_barrier()
#define LGK0() do{ asm volatile("s_waitcnt lgkmcnt(0)" ::: "memory"); __builtin_amdgcn_sched_barrier(0); }while(0)
#define VMC4() do{ asm volatile("s_waitcnt vmcnt(4)" ::: "memory"); __builtin_amdgcn_sched_barrier(0); }while(0)
#define VMC0() do{ asm volatile("s_waitcnt vmcnt(0)" ::: "memory"); __builtin_amdgcn_sched_barrier(0); }while(0)

// 0.125 * log2(e): folded into Q so attention uses exp2 directly
#define QSCALE 0.1803368801111183f

// ---------------- embed gather ----------------
__global__ __launch_bounds__(256) void embed_k(const float* __restrict__ emb,
                                               const int* __restrict__ tokens,
                                               float* __restrict__ x){
  int t = blockIdx.x;
  int tok = tokens[t];
  const float4* src = (const float4*)(emb + (size_t)tok * E_DIM);
  float4* dst = (float4*)(x + (size_t)t * E_DIM);
  dst[threadIdx.x] = src[threadIdx.x];
}

// ---------------- transpose + fp32->bf16: dst[c][r] = src[r][c] (head only) ----------------
__global__ __launch_bounds__(256) void transpose_bf16(const float* __restrict__ src,
                                                      unsigned short* __restrict__ dst,
                                                      int R, int C){
  __shared__ float tile[32][33];
  int c0 = blockIdx.x * 32, r0 = blockIdx.y * 32;
  int tx = threadIdx.x & 31, ty = threadIdx.x >> 5;
  for (int i = 0; i < 4; i++){
    int r = ty + i * 8;
    tile[r][tx] = src[(size_t)(r0 + r) * C + c0 + tx];
  }
  __syncthreads();
  for (int i = 0; i < 4; i++){
    int r = ty + i * 8;
    dst[(size_t)(c0 + r) * R + r0 + tx] = f2bf(tile[tx][r]);
  }
}

// ---------------- per-layer weight prep: all transposes in ONE launch ----------------
__device__ __forceinline__ void tr32(const float* __restrict__ src, unsigned short* __restrict__ dst,
                                     int R, int C, int bx, int by, float* tile /*32x33*/){
  int c0 = bx * 32, r0 = by * 32;
  int tx = threadIdx.x & 31, ty = threadIdx.x >> 5;
  for (int i = 0; i < 4; i++){
    int r = ty + i * 8;
    tile[r * 33 + tx] = src[(size_t)(r0 + r) * C + c0 + tx];
  }
  __syncthreads();
  for (int i = 0; i < 4; i++){
    int r = ty + i * 8;
    dst[(size_t)(c0 + r) * R + r0 + tx] = f2bf(tile[tx * 33 + r]);
  }
}

// wt_f12i layout: row n' (0..8191): q=n'/32, r=n'%32; r<16 -> f1 col q*16+r ; r>=16 -> f2 col q*16+(r-16)
__global__ __launch_bounds__(256) void prep_weights(const float* __restrict__ Wq, const float* __restrict__ Wk,
                                                    const float* __restrict__ Wv, const float* __restrict__ Wo,
                                                    const float* __restrict__ f1, const float* __restrict__ f2,
                                                    const float* __restrict__ f3,
                                                    unsigned short* __restrict__ wt_qkv,
                                                    unsigned short* __restrict__ wt_o,
                                                    unsigned short* __restrict__ wt_f12i,
                                                    unsigned short* __restrict__ wt_f3){
  __shared__ float sh[1100];
  int id = blockIdx.x;
  if (id < 2048){ tr32(Wq, wt_qkv, 1024, 2048, id & 63, id >> 6, sh); return; }
  id -= 2048;
  if (id < 256){ tr32(Wk, wt_qkv + 2048 * 1024, 1024, 256, id & 7, id >> 3, sh); return; }
  id -= 256;
  if (id < 256){ tr32(Wv, wt_qkv + 2304 * 1024, 1024, 256, id & 7, id >> 3, sh); return; }
  id -= 256;
  if (id < 1024){ tr32(Wo, wt_o, 1024, 1024, id & 31, id >> 5, sh); return; }
  id -= 1024;
  if (id < 4096){ tr32(f3, wt_f3, 4096, 1024, id & 31, id >> 5, sh); return; }
  id -= 4096;
  {
    int q = id & 255, kb = id >> 8;
    float* t1 = sh; float* t2 = sh + 32 * 17;
    int c = threadIdx.x & 15, kk0 = threadIdx.x >> 4;
    for (int p = 0; p < 2; p++){
      int kk = p * 16 + kk0;
      t1[kk * 17 + c] = f1[(size_t)(kb * 32 + kk) * F_DIM + q * 16 + c];
      t2[kk * 17 + c] = f2[(size_t)(kb * 32 + kk) * F_DIM + q * 16 + c];
    }
    __syncthreads();
    int kk = threadIdx.x & 31, rb = threadIdx.x >> 5;
    for (int i = 0; i < 4; i++){
      int r = i * 8 + rb;
      float v = (r < 16) ? t1[kk * 17 + r] : t2[kk * 17 + (r - 16)];
      wt_f12i[(size_t)(q * 32 + r) * 1024 + kb * 32 + kk] = f2bf(v);
    }
  }
}

// ---------------- rmsnorm (row of 1024) fp32 -> bf16, out = n*(1+w) ----------------
__global__ __launch_bounds__(256) void rmsnorm_k(const float* __restrict__ x,
                                                 const float* __restrict__ w,
                                                 unsigned short* __restrict__ out){
  const int t = blockIdx.x, tid = threadIdx.x;
  const float4 v = ((const float4*)(x + (size_t)t * E_DIM))[tid];
  float ss = v.x*v.x + v.y*v.y + v.z*v.z + v.w*v.w;
  for (int m = 1; m < 64; m <<= 1) ss += __shfl_xor(ss, m);
  __shared__ float red[4];
  if ((tid & 63) == 0) red[tid >> 6] = ss;
  __syncthreads();
  ss = red[0] + red[1] + red[2] + red[3];
  const float r = rsqrtf(ss * (1.0f / E_DIM) + 1e-6f);
  const float4 wv = ((const float4*)w)[tid];
  ushort4 o;
  o.x = f2bf(v.x * r * (1.0f + wv.x));
  o.y = f2bf(v.y * r * (1.0f + wv.y));
  o.z = f2bf(v.z * r * (1.0f + wv.z));
  o.w = f2bf(v.w * r * (1.0f + wv.w));
  ((ushort4*)(out + (size_t)t * E_DIM))[tid] = o;
}

// ================= 64x128 GEMM (m97 structure, 256 thr) — small-N matmuls =================
template<bool ADD>
__global__ __launch_bounds__(256) void gemm64_bt(const unsigned short* __restrict__ A,
                                                 const unsigned short* __restrict__ Bt,
                                                 float* __restrict__ C,
                                                 int M, int N, int K){
  __shared__ unsigned short As[64 * 32];
  __shared__ unsigned short Bs[128 * 32];
  const int tid = threadIdx.x;
  const int lane = tid & 63, w = tid >> 6;
  const int l15 = lane & 15, l4 = lane >> 4;

  const int chunk = gridDim.x >> 3;
  const int wgid = (blockIdx.x & 7) * chunk + (blockIdx.x >> 3);
  const int nm = M >> 6;
  const int bm = wgid % nm, bn = wgid / nm;
  const int m0 = bm * 64, n0 = bn * 128;

  const int r0 = tid >> 2;
  const int c0 = (tid & 3) << 3;

  const unsigned short* gA  = A  + (size_t)(m0 + r0) * K + c0;
  const unsigned short* gB0 = Bt + (size_t)(n0 + r0) * K + c0;
  const unsigned short* gB1 = Bt + (size_t)(n0 + 64 + r0) * K + c0;
  unsigned short* lA  = As + w * 512;
  unsigned short* lB0 = Bs + w * 512;
  unsigned short* lB1 = Bs + 2048 + w * 512;

  f32x4 acc[4][2] = {};

  for (int k0 = 0; k0 < K; k0 += 32){
    __syncthreads();
    gl16(gA  + k0, lA);
    gl16(gB0 + k0, lB0);
    gl16(gB1 + k0, lB1);
    __syncthreads();
    bf16x8 af[4], bfr[2];
    for (int i = 0; i < 4; i++)
      af[i] = *(const bf16x8*)&As[(i * 16 + l15) * 32 + l4 * 8];
    for (int j = 0; j < 2; j++)
      bfr[j] = *(const bf16x8*)&Bs[(w * 32 + j * 16 + l15) * 32 + l4 * 8];
    for (int i = 0; i < 4; i++)
      for (int j = 0; j < 2; j++)
        acc[i][j] = mfma16(af[i], bfr[j], acc[i][j]);
  }

  for (int i = 0; i < 4; i++)
    for (int j = 0; j < 2; j++){
      int col = n0 + w * 32 + j * 16 + l15;
      for (int r = 0; r < 4; r++){
        int row = m0 + i * 16 + l4 * 4 + r;
        size_t idx = (size_t)row * N + col;
        if (ADD) C[idx] += acc[i][j][r]; else C[idx] = acc[i][j][r];
      }
    }
}

// ================= 256x256 8-phase GEMM (T2+T3+T4+T5) =================
// EPI=0: fp32 store to outF[M][N-stride]. EPI=1: f1/f2-interleaved silu-mul epilogue -> bf16 outH.
// Bijective XCD swizzle (m204) — valid for any grid size.
template<int EPI>
__global__ __launch_bounds__(512, 2) void gemm256(const unsigned short* __restrict__ A,
                                                  const unsigned short* __restrict__ Bt,
                                                  float* __restrict__ outF,
                                                  unsigned short* __restrict__ outH,
                                                  int M, int N, int K){
  __shared__ unsigned short lds[65536];  // 128 KiB
  const int tid = threadIdx.x;
  const int lane = tid & 63, w = tid >> 6;
  const int wm = w >> 2, wn = w & 3;
  const int l15 = lane & 15, l4 = lane >> 4;

  const int nwg = gridDim.x;
  const int xcd = (int)blockIdx.x & 7, lin = (int)blockIdx.x >> 3;
  const int q8 = nwg >> 3, r8 = nwg & 7;
  const int wgid = (xcd < r8 ? xcd * (q8 + 1) : r8 * (q8 + 1) + (xcd - r8) * q8) + lin;
  const int nm = M >> 8;
  const int bm = wgid % nm, bn = wgid / nm;
  const int m0 = bm * 256, n0 = bn * 256;
  const int NT = K >> 6;

  const int srow = (lane >> 3);
  const int scol = lane & 7;

  auto stageA = [&](int b, int h, int kt){
    #pragma unroll
    for (int c = 0; c < 2; c++){
      int r = w * 16 + c * 8 + srow;
      const unsigned short* g = A + (size_t)(m0 + h * 128 + r) * K + kt * 64 + ((scol ^ (r & 7)) << 3);
      gl16(g, (char*)lds + (b * 2 + h) * 16384 + (w * 16 + c * 8) * 128);
    }
  };
  auto stageB = [&](int b, int h, int kt){
    #pragma unroll
    for (int c = 0; c < 2; c++){
      int r = w * 16 + c * 8 + srow;
      const unsigned short* g = Bt + (size_t)(n0 + h * 128 + r) * K + kt * 64 + ((scol ^ (r & 7)) << 3);
      gl16(g, (char*)lds + 65536 + (b * 2 + h) * 16384 + (w * 16 + c * 8) * 128);
    }
  };

  const int sl0 = ((l4)     ^ (l15 & 7)) << 4;
  const int sl1 = ((4 | l4) ^ (l15 & 7)) << 4;

  f32x4 acc[8][4] = {};
  bf16x8 aF[8], bF[8];

  stageA(0, 0, 0); stageA(0, 1, 0); stageB(0, 0, 0); stageB(0, 1, 0);
  if (NT > 1){ stageB(1, 0, 1); stageB(1, 1, 1); }
  VMC4();
  SBAR();

  for (int kt = 0; kt < NT; kt++){
    const int buf = kt & 1;
    const char* Ab = (const char*)lds + (buf * 2 + wm) * 16384;
    const char* Bb = (const char*)lds + 65536 + (buf * 2 + (wn >> 1)) * 16384;
    const int brbase = (wn & 1) * 64;

    // PH1
    #pragma unroll
    for (int mf = 0; mf < 4; mf++){
      int r = mf * 16 + l15;
      aF[mf * 2 + 0] = *(const bf16x8*)(Ab + r * 128 + sl0);
      aF[mf * 2 + 1] = *(const bf16x8*)(Ab + r * 128 + sl1);
    }
    #pragma unroll
    for (int nf = 0; nf < 2; nf++){
      int r = brbase + nf * 16 + l15;
      bF[nf * 2 + 0] = *(const bf16x8*)(Bb + r * 128 + sl0);
      bF[nf * 2 + 1] = *(const bf16x8*)(Bb + r * 128 + sl1);
    }
    if (kt + 1 < NT) stageA(buf ^ 1, 0, kt + 1);
    SBAR(); LGK0();
    __builtin_amdgcn_s_setprio(1);
    #pragma unroll
    for (int mf = 0; mf < 4; mf++)
      #pragma unroll
      for (int nf = 0; nf < 2; nf++){
        acc[mf][nf] = mfma16(aF[mf * 2 + 0], bF[nf * 2 + 0], acc[mf][nf]);
        acc[mf][nf] = mfma16(aF[mf * 2 + 1], bF[nf * 2 + 1], acc[mf][nf]);
      }
    __builtin_amdgcn_s_setprio(0);
    SBAR();

    // PH2
    #pragma unroll
    for (int nf = 2; nf < 4; nf++){
      int r = brbase + nf * 16 + l15;
      bF[nf * 2 + 0] = *(const bf16x8*)(Bb + r * 128 + sl0);
      bF[nf * 2 + 1] = *(const bf16x8*)(Bb + r * 128 + sl1);
    }
    if (kt + 1 < NT) stageA(buf ^ 1, 1, kt + 1);
    SBAR(); LGK0();
    __builtin_amdgcn_s_setprio(1);
    #pragma unroll
    for (int mf = 0; mf < 4; mf++)
      #pragma unroll
      for (int nf = 2; nf < 4; nf++){
        acc[mf][nf] = mfma16(aF[mf * 2 + 0], bF[nf * 2 + 0], acc[mf][nf]);
        acc[mf][nf] = mfma16(aF[mf * 2 + 1], bF[nf * 2 + 1], acc[mf][nf]);
      }
    __builtin_amdgcn_s_setprio(0);
    SBAR();

    // PH3
    #pragma unroll
    for (int mf = 0; mf < 4; mf++){
      int r = 64 + mf * 16 + l15;
      aF[mf * 2 + 0] = *(const bf16x8*)(Ab + r * 128 + sl0);
      aF[mf * 2 + 1] = *(const bf16x8*)(Ab + r * 128 + sl1);
    }
    if (kt + 2 < NT) stageB(buf, 0, kt + 2);
    SBAR(); LGK0();
    __builtin_amdgcn_s_setprio(1);
    #pragma unroll
    for (int mf = 0; mf < 4; mf++)
      #pragma unroll
      for (int nf = 2; nf < 4; nf++){
        acc[4 + mf][nf] = mfma16(aF[mf * 2 + 0], bF[nf * 2 + 0], acc[4 + mf][nf]);
        acc[4 + mf][nf] = mfma16(aF[mf * 2 + 1], bF[nf * 2 + 1], acc[4 + mf][nf]);
      }
    __builtin_amdgcn_s_setprio(0);
    SBAR();

    // PH4
    if (kt + 2 < NT) stageB(buf, 1, kt + 2);
    SBAR();
    __builtin_amdgcn_s_setprio(1);
    #pragma unroll
    for (int mf = 0; mf < 4; mf++)
      #pragma unroll
      for (int nf = 0; nf < 2; nf++){
        acc[4 + mf][nf] = mfma16(aF[mf * 2 + 0], bF[nf * 2 + 0], acc[4 + mf][nf]);
        acc[4 + mf][nf] = mfma16(aF[mf * 2 + 1], bF[nf * 2 + 1], acc[4 + mf][nf]);
      }
    __builtin_amdgcn_s_setprio(0);
    if (kt + 2 < NT) { VMC4(); } else { VMC0(); }
    SBAR();
  }

  if (EPI == 0){
    #pragma unroll
    for (int mfg = 0; mfg < 8; mfg++){
      #pragma unroll
      for (int nf = 0; nf < 4; nf++){
        int col = n0 + wn * 64 + nf * 16 + l15;
        int row0 = m0 + wm * 128 + mfg * 16 + l4 * 4;
        #pragma unroll
        for (int r = 0; r < 4; r++)
          outF[(size_t)(row0 + r) * N + col] = acc[mfg][nf][r];
      }
    }
  } else {
    const int NH = N >> 1;
    #pragma unroll
    for (int mfg = 0; mfg < 8; mfg++){
      #pragma unroll
      for (int nfp = 0; nfp < 2; nfp++){
        int col = (n0 >> 1) + wn * 32 + nfp * 16 + l15;
        int row0 = m0 + wm * 128 + mfg * 16 + l4 * 4;
        #pragma unroll
        for (int r = 0; r < 4; r++){
          float u = acc[mfg][nfp * 2 + 0][r];
          float g = acc[mfg][nfp * 2 + 1][r];
          outH[(size_t)(row0 + r) * NH + col] = f2bf(u / (1.0f + __expf(-u)) * g);
        }
      }
    }
  }
}

// ---------------- q/k norm + rope + v transpose (Q pre-scaled by 0.125*log2e) ----------------
__global__ __launch_bounds__(256) void qkvpost_k(const float* __restrict__ qkv,
                                                 const float* __restrict__ qn,
                                                 const float* __restrict__ kn,
                                                 unsigned short* __restrict__ qb,
                                                 unsigned short* __restrict__ kb,
                                                 unsigned short* __restrict__ vt){
  const int t = blockIdx.x;
  const int lane = threadIdx.x & 63, w = threadIdx.x >> 6;
  const int d = lane;
  const int fi = d & 7;
  const float invf = powf(10000.0f, -(float)fi * 0.125f);
  const float ang = (float)t * invf;
  const float c = cosf(ang), s = sinf(ang);

  for (int i = 0; i < 4; i++){
    int h = w * 4 + i;
    float v = qkv[(size_t)t * 2560 + h * 128 + d];
    float ss = v * v;
    for (int m = 1; m < 64; m <<= 1) ss += __shfl_xor(ss, m);
    float r = rsqrtf(ss * (1.0f / D_H) + 1e-6f);
    float xn = v * r * (1.0f + qn[d]);
    float partner = __shfl_xor(xn, 8);
    float o;
    if (d < 8)       o = xn * c - partner * s;
    else if (d < 16) o = xn * c + partner * s;
    else             o = xn;
    qb[((size_t)h * T_LEN + t) * D_H + d] = f2bf(o * QSCALE);
  }
  {
    float v = qkv[(size_t)t * 2560 + 2048 + w * 64 + d];
    float ss = v * v;
    for (int m = 1; m < 64; m <<= 1) ss += __shfl_xor(ss, m);
    float r = rsqrtf(ss * (1.0f / D_H) + 1e-6f);
    float xn = v * r * (1.0f + kn[d]);
    float partner = __shfl_xor(xn, 8);
    float o;
    if (d < 8)       o = xn * c - partner * s;
    else if (d < 16) o = xn * c + partner * s;
    else             o = xn;
    kb[((size_t)w * T_LEN + t) * D_H + d] = f2bf(o);
  }
  {
    float v = qkv[(size_t)t * 2560 + 2304 + w * 64 + d];
    vt[((size_t)(w * 64 + d)) * T_LEN + t] = f2bf(v);
  }
}

// ---------------- flash attention, KV-split: block = (qt, h, chunk of 256 kv) ----------------
// Writes unnormalized partial O + (m, l) per chunk; combine kernel merges.
__global__ __launch_bounds__(64) void attn_k(const unsigned short* __restrict__ qb,
                                             const unsigned short* __restrict__ kb,
                                             const unsigned short* __restrict__ vt,
                                             float* __restrict__ po,
                                             float* __restrict__ pm,
                                             float* __restrict__ pl){
  const int qt = blockIdx.x, h = blockIdx.y, c = blockIdx.z;
  const int nch = (qt >> 4) + 1;
  if (c >= nch) return;
  const int g = h >> 2;
  const int lane = threadIdx.x;
  const int l15 = lane & 15, l4 = lane >> 4;
  const int q0 = qt * 16;
  const int kvbeg = c << 8;
  const int kvend = min(kvbeg + 256, q0 + 16);
  __shared__ unsigned short Pl[16][72];

  const bf16x8 aq0 = *(const bf16x8*)(qb + ((size_t)h * T_LEN + q0 + l15) * D_H + l4 * 8);
  const bf16x8 aq1 = *(const bf16x8*)(qb + ((size_t)h * T_LEN + q0 + l15) * D_H + 32 + l4 * 8);

  f32x4 acc[4] = {};
  float mrun[4], lpart[4];
  for (int j = 0; j < 4; j++){ mrun[j] = -1e30f; lpart[j] = 0.0f; }

  for (int kv0 = kvbeg; kv0 < kvend; kv0 += 64){
    f32x4 sc[4];
    #pragma unroll
    for (int cp = 0; cp < 4; cp++){
      const unsigned short* kbase = kb + ((size_t)g * T_LEN + kv0 + cp * 16 + l15) * D_H + l4 * 8;
      bf16x8 bk0 = *(const bf16x8*)(kbase);
      bf16x8 bk1 = *(const bf16x8*)(kbase + 32);
      f32x4 z = {0.f, 0.f, 0.f, 0.f};
      z = mfma16(aq0, bk0, z);
      z = mfma16(aq1, bk1, z);
      sc[cp] = z;
    }
    float resc[4];
    #pragma unroll
    for (int j = 0; j < 4; j++){
      int r = q0 + l4 * 4 + j;
      #pragma unroll
      for (int cp = 0; cp < 4; cp++){
        int col = kv0 + cp * 16 + l15;
        sc[cp][j] = (col <= r) ? sc[cp][j] : -1e30f;
      }
      float mx = fmaxf(fmaxf(sc[0][j], sc[1][j]), fmaxf(sc[2][j], sc[3][j]));
      for (int off = 1; off < 16; off <<= 1) mx = fmaxf(mx, __shfl_xor(mx, off));
      float mnew = fmaxf(mrun[j], mx);
      resc[j] = exp2f(mrun[j] - mnew);
      mrun[j] = mnew;
      float ssum = 0.0f;
      #pragma unroll
      for (int cp = 0; cp < 4; cp++){
        float pv = exp2f(sc[cp][j] - mnew);
        sc[cp][j] = pv;
        ssum += pv;
      }
      lpart[j] = lpart[j] * resc[j] + ssum;
      #pragma unroll
      for (int nt = 0; nt < 4; nt++) acc[nt][j] *= resc[j];
    }
    __syncthreads();
    #pragma unroll
    for (int j = 0; j < 4; j++)
      #pragma unroll
      for (int cp = 0; cp < 4; cp++)
        Pl[l4 * 4 + j][cp * 16 + l15] = f2bf(sc[cp][j]);
    __syncthreads();
    const bf16x8 pa0 = *(const bf16x8*)&Pl[l15][l4 * 8];
    const bf16x8 pa1 = *(const bf16x8*)&Pl[l15][32 + l4 * 8];
    #pragma unroll
    for (int nt = 0; nt < 4; nt++){
      const unsigned short* vbase = vt + ((size_t)g * 64 + nt * 16 + l15) * T_LEN + kv0;
      bf16x8 bv0 = *(const bf16x8*)(vbase + l4 * 8);
      bf16x8 bv1 = *(const bf16x8*)(vbase + 32 + l4 * 8);
      acc[nt] = mfma16(pa1, bv1, mfma16(pa0, bv0, acc[nt]));
    }
  }

  #pragma unroll
  for (int j = 0; j < 4; j++)
    for (int off = 1; off < 16; off <<= 1) lpart[j] += __shfl_xor(lpart[j], off);

  const int pidx = ((h << 7) + qt) * 8 + c;
  float* poB = po + (size_t)pidx * (16 * 64);
  #pragma unroll
  for (int j = 0; j < 4; j++){
    int row = l4 * 4 + j;
    #pragma unroll
    for (int nt = 0; nt < 4; nt++)
      poB[row * 64 + nt * 16 + l15] = acc[nt][j];
  }
  if (l15 == 0){
    #pragma unroll
    for (int j = 0; j < 4; j++){
      pm[pidx * 16 + l4 * 4 + j] = mrun[j];
      pl[pidx * 16 + l4 * 4 + j] = lpart[j];
    }
  }
}

// ---------------- combine partials + normalize + sigmoid gate ----------------
__global__ __launch_bounds__(64) void attn_combine(const float* __restrict__ po,
                                                   const float* __restrict__ pm,
                                                   const float* __restrict__ pl,
                                                   const float* __restrict__ qkv,
                                                   unsigned short* __restrict__ ctxg){
  const int qt = blockIdx.x, h = blockIdx.y;
  const int nch = (qt >> 4) + 1;
  const int d = threadIdx.x;
  const int q0 = qt << 4;
  const int base = ((h << 7) + qt) * 8;
  for (int r = 0; r < 16; r++){
    float mstar = -1e30f;
    for (int c = 0; c < nch; c++) mstar = fmaxf(mstar, pm[(base + c) * 16 + r]);
    float accv = 0.f, lsum = 0.f;
    for (int c = 0; c < nch; c++){
      float wgt = exp2f(pm[(base + c) * 16 + r] - mstar);
      accv += wgt * po[(size_t)(base + c) * 1024 + r * 64 + d];
      lsum += wgt * pl[(base + c) * 16 + r];
    }
    float gate = qkv[(size_t)(q0 + r) * 2560 + h * 128 + 64 + d];
    float val = accv / lsum * (1.0f / (1.0f + __expf(-gate)));
    ctxg[(size_t)(q0 + r) * (H_N * D_H) + h * D_H + d] = f2bf(val);
  }
}

extern "C" void kernel_launch(void* const* d_in, const int* in_sizes, int n_in,
                              void* d_out, int out_size, void* d_ws, size_t ws_size,
                              hipStream_t stream){
  (void)in_sizes; (void)n_in; (void)out_size; (void)ws_size;
  const int*   tokens = (const int*)d_in[0];
  const float* emb    = (const float*)d_in[1];
  const float* Wq     = (const float*)d_in[2];
  const float* Wk     = (const float*)d_in[3];
  const float* Wv     = (const float*)d_in[4];
  const float* Wo     = (const float*)d_in[5];
  const float* qn     = (const float*)d_in[6];
  const float* kn     = (const float*)d_in[7];
  const float* n1     = (const float*)d_in[8];
  const float* n2     = (const float*)d_in[9];
  const float* f1     = (const float*)d_in[10];
  const float* f2     = (const float*)d_in[11];
  const float* f3     = (const float*)d_in[12];
  const float* fn     = (const float*)d_in[13];
  const float* head   = (const float*)d_in[14];
  float* out = (float*)d_out;

  char* ws = (char*)d_ws;
  size_t off = 0;
  auto alloc = [&](size_t bytes)->char*{
    char* p = ws + off;
    off += (bytes + 255) & ~(size_t)255;
    return p;
  };
  float*          x       = (float*)alloc((size_t)T_LEN * E_DIM * 4);
  unsigned short* hbf     = (unsigned short*)alloc((size_t)T_LEN * E_DIM * 2);
  float*          qkvf    = (float*)alloc((size_t)T_LEN * 2560 * 4);
  unsigned short* qb      = (unsigned short*)alloc((size_t)H_N * T_LEN * D_H * 2);
  unsigned short* kb      = (unsigned short*)alloc((size_t)G_N * T_LEN * D_H * 2);
  unsigned short* vt      = (unsigned short*)alloc((size_t)G_N * D_H * T_LEN * 2);
  unsigned short* ctxg    = (unsigned short*)alloc((size_t)T_LEN * E_DIM * 2);
  unsigned short* hg      = (unsigned short*)alloc((size_t)T_LEN * F_DIM * 2);
  float*          po      = (float*)alloc((size_t)H_N * 128 * 8 * 16 * 64 * 4);
  float*          pm      = (float*)alloc((size_t)H_N * 128 * 8 * 16 * 4);
  float*          pl      = (float*)alloc((size_t)H_N * 128 * 8 * 16 * 4);
  unsigned short* wt_qkv  = (unsigned short*)alloc((size_t)2560 * E_DIM * 2);
  unsigned short* wt_o    = (unsigned short*)alloc((size_t)E_DIM * E_DIM * 2);
  unsigned short* wt_f12i = (unsigned short*)alloc((size_t)2 * F_DIM * E_DIM * 2);
  unsigned short* wt_f3   = (unsigned short*)alloc((size_t)E_DIM * F_DIM * 2);
  unsigned short* wt_head = (unsigned short*)alloc((size_t)V_SZ * E_DIM * 2);

  embed_k<<<T_LEN, 256, 0, stream>>>(emb, tokens, x);
  transpose_bf16<<<dim3(V_SZ / 32, E_DIM / 32), 256, 0, stream>>>(head, wt_head, E_DIM, V_SZ);

  for (int l = 0; l < L_N; l++){
    prep_weights<<<15872, 256, 0, stream>>>(Wq + (size_t)l * E_DIM * 2048,
                                            Wk + (size_t)l * E_DIM * 256,
                                            Wv + (size_t)l * E_DIM * 256,
                                            Wo + (size_t)l * E_DIM * E_DIM,
                                            f1 + (size_t)l * E_DIM * F_DIM,
                                            f2 + (size_t)l * E_DIM * F_DIM,
                                            f3 + (size_t)l * F_DIM * E_DIM,
                                            wt_qkv, wt_o, wt_f12i, wt_f3);

    rmsnorm_k<<<T_LEN, 256, 0, stream>>>(x, n1 + l * E_DIM, hbf);
    gemm64_bt<false><<<(T_LEN / 64) * (2560 / 128), 256, 0, stream>>>(hbf, wt_qkv, qkvf, T_LEN, 2560, E_DIM);
    qkvpost_k<<<T_LEN, 256, 0, stream>>>(qkvf, qn + l * D_H, kn + l * D_H, qb, kb, vt);
    attn_k<<<dim3(T_LEN / 16, H_N, 8), 64, 0, stream>>>(qb, kb, vt, po, pm, pl);
    attn_combine<<<dim3(T_LEN / 16, H_N), 64, 0, stream>>>(po, pm, pl, qkvf, ctxg);
    gemm64_bt<true><<<(T_LEN / 64) * (E_DIM / 128), 256, 0, stream>>>(ctxg, wt_o, x, T_LEN, E_DIM, E_DIM);

    rmsnorm_k<<<T_LEN, 256, 0, stream>>>(x, n2 + l * E_DIM, hbf);
    gemm256<1><<<(T_LEN / 256) * (2 * F_DIM / 256), 512, 0, stream>>>(hbf, wt_f12i, nullptr, hg, T_LEN, 2 * F_DIM, E_DIM);
    gemm64_bt<true><<<(T_LEN / 64) * (E_DIM / 128), 256, 0, stream>>>(hg, wt_f3, x, T_LEN, E_DIM, F_DIM);
  }

  rmsnorm_k<<<T_LEN, 256, 0, stream>>>(x, fn, hbf);
  // head split into two N-halves (63 + 62 col-blocks) for profiler visibility; stride stays V_SZ
  gemm256<0><<<(T_LEN / 256) * 63, 512, 0, stream>>>(hbf, wt_head, out, nullptr, T_LEN, V_SZ, E_DIM);
  gemm256<0><<<(T_LEN / 256) * 62, 512, 0, stream>>>(hbf, wt_head + (size_t)(63 * 256) * E_DIM,
                                                     out + (size_t)(63 * 256), nullptr, T_LEN, V_SZ, E_DIM);
}

// Round 8
// 1411.589 us; speedup vs baseline: 1.1645x; 1.1645x over previous
//
#include <hip/hip_runtime.h>

#define T_LEN 2048
#define E_DIM 1024
#define H_N 16
#define G_N 4
#define D_H 64
#define F_DIM 4096
#define V_SZ 32000
#define L_N 4

typedef __attribute__((ext_vector_type(8))) __bf16 bf16x8;
typedef __attribute__((ext_vector_type(4))) float f32x4;

__device__ __forceinline__ unsigned short f2bf(float f){
  unsigned int u = __float_as_uint(f);
  unsigned int r = (u + 0x7FFFu + ((u >> 16) & 1u)) >> 16;
  return (unsigned short)r;
}

__device__ __forceinline__ f32x4 mfma16(bf16x8 a, bf16x8 b, f32x4 c){
  return __builtin_amdgcn_mfma_f32_16x16x32_bf16(a, b, c, 0, 0, 0);
}

__device__ __forceinline__ void gl16(const void* g, void* l){
  __builtin_amdgcn_global_load_lds((const __attribute__((address_space(1))) void*)g,
                                   (__attribute__((address_space(3))) void*)l, 16, 0, 0);
}

#define SBAR() __builtin_amdgcn_s_barrier()
#define LGK0() do{ asm volatile("s_waitcnt lgkmcnt(0)" ::: "memory"); __builtin_amdgcn_sched_barrier(0); }while(0)
#define VMC4() do{ asm volatile("s_waitcnt vmcnt(4)" ::: "memory"); __builtin_amdgcn_sched_barrier(0); }while(0)
#define VMC0() do{ asm volatile("s_waitcnt vmcnt(0)" ::: "memory"); __builtin_amdgcn_sched_barrier(0); }while(0)

// 0.125 * log2(e): folded into Q so attention uses exp2 directly
#define QSCALE 0.1803368801111183f

// ---------------- embed gather ----------------
__global__ __launch_bounds__(256) void embed_k(const float* __restrict__ emb,
                                               const int* __restrict__ tokens,
                                               float* __restrict__ x){
  int t = blockIdx.x;
  int tok = tokens[t];
  const float4* src = (const float4*)(emb + (size_t)tok * E_DIM);
  float4* dst = (float4*)(x + (size_t)t * E_DIM);
  dst[threadIdx.x] = src[threadIdx.x];
}

// ---------------- transpose + fp32->bf16: dst[c][r] = src[r][c] (head only) ----------------
__global__ __launch_bounds__(256) void transpose_bf16(const float* __restrict__ src,
                                                      unsigned short* __restrict__ dst,
                                                      int R, int C){
  __shared__ float tile[32][33];
  int c0 = blockIdx.x * 32, r0 = blockIdx.y * 32;
  int tx = threadIdx.x & 31, ty = threadIdx.x >> 5;
  for (int i = 0; i < 4; i++){
    int r = ty + i * 8;
    tile[r][tx] = src[(size_t)(r0 + r) * C + c0 + tx];
  }
  __syncthreads();
  for (int i = 0; i < 4; i++){
    int r = ty + i * 8;
    dst[(size_t)(c0 + r) * R + r0 + tx] = f2bf(tile[tx][r]);
  }
}

// ---------------- per-layer weight prep: all transposes in ONE launch ----------------
__device__ __forceinline__ void tr32(const float* __restrict__ src, unsigned short* __restrict__ dst,
                                     int R, int C, int bx, int by, float* tile /*32x33*/){
  int c0 = bx * 32, r0 = by * 32;
  int tx = threadIdx.x & 31, ty = threadIdx.x >> 5;
  for (int i = 0; i < 4; i++){
    int r = ty + i * 8;
    tile[r * 33 + tx] = src[(size_t)(r0 + r) * C + c0 + tx];
  }
  __syncthreads();
  for (int i = 0; i < 4; i++){
    int r = ty + i * 8;
    dst[(size_t)(c0 + r) * R + r0 + tx] = f2bf(tile[tx * 33 + r]);
  }
}

// wt_f12i layout: row n' (0..8191): q=n'/32, r=n'%32; r<16 -> f1 col q*16+r ; r>=16 -> f2 col q*16+(r-16)
__global__ __launch_bounds__(256) void prep_weights(const float* __restrict__ Wq, const float* __restrict__ Wk,
                                                    const float* __restrict__ Wv, const float* __restrict__ Wo,
                                                    const float* __restrict__ f1, const float* __restrict__ f2,
                                                    const float* __restrict__ f3,
                                                    unsigned short* __restrict__ wt_qkv,
                                                    unsigned short* __restrict__ wt_o,
                                                    unsigned short* __restrict__ wt_f12i,
                                                    unsigned short* __restrict__ wt_f3){
  __shared__ float sh[1100];
  int id = blockIdx.x;
  if (id < 2048){ tr32(Wq, wt_qkv, 1024, 2048, id & 63, id >> 6, sh); return; }
  id -= 2048;
  if (id < 256){ tr32(Wk, wt_qkv + 2048 * 1024, 1024, 256, id & 7, id >> 3, sh); return; }
  id -= 256;
  if (id < 256){ tr32(Wv, wt_qkv + 2304 * 1024, 1024, 256, id & 7, id >> 3, sh); return; }
  id -= 256;
  if (id < 1024){ tr32(Wo, wt_o, 1024, 1024, id & 31, id >> 5, sh); return; }
  id -= 1024;
  if (id < 4096){ tr32(f3, wt_f3, 4096, 1024, id & 31, id >> 5, sh); return; }
  id -= 4096;
  {
    int q = id & 255, kb = id >> 8;
    float* t1 = sh; float* t2 = sh + 32 * 17;
    int c = threadIdx.x & 15, kk0 = threadIdx.x >> 4;
    for (int p = 0; p < 2; p++){
      int kk = p * 16 + kk0;
      t1[kk * 17 + c] = f1[(size_t)(kb * 32 + kk) * F_DIM + q * 16 + c];
      t2[kk * 17 + c] = f2[(size_t)(kb * 32 + kk) * F_DIM + q * 16 + c];
    }
    __syncthreads();
    int kk = threadIdx.x & 31, rb = threadIdx.x >> 5;
    for (int i = 0; i < 4; i++){
      int r = i * 8 + rb;
      float v = (r < 16) ? t1[kk * 17 + r] : t2[kk * 17 + (r - 16)];
      wt_f12i[(size_t)(q * 32 + r) * 1024 + kb * 32 + kk] = f2bf(v);
    }
  }
}

// ---------------- rmsnorm (row of 1024) fp32 -> bf16, out = n*(1+w) ----------------
__global__ __launch_bounds__(256) void rmsnorm_k(const float* __restrict__ x,
                                                 const float* __restrict__ w,
                                                 unsigned short* __restrict__ out){
  const int t = blockIdx.x, tid = threadIdx.x;
  const float4 v = ((const float4*)(x + (size_t)t * E_DIM))[tid];
  float ss = v.x*v.x + v.y*v.y + v.z*v.z + v.w*v.w;
  for (int m = 1; m < 64; m <<= 1) ss += __shfl_xor(ss, m);
  __shared__ float red[4];
  if ((tid & 63) == 0) red[tid >> 6] = ss;
  __syncthreads();
  ss = red[0] + red[1] + red[2] + red[3];
  const float r = rsqrtf(ss * (1.0f / E_DIM) + 1e-6f);
  const float4 wv = ((const float4*)w)[tid];
  ushort4 o;
  o.x = f2bf(v.x * r * (1.0f + wv.x));
  o.y = f2bf(v.y * r * (1.0f + wv.y));
  o.z = f2bf(v.z * r * (1.0f + wv.z));
  o.w = f2bf(v.w * r * (1.0f + wv.w));
  ((ushort4*)(out + (size_t)t * E_DIM))[tid] = o;
}

// ================= 64x128 GEMM (m97 structure, 256 thr) — small-N matmuls =================
template<bool ADD>
__global__ __launch_bounds__(256) void gemm64_bt(const unsigned short* __restrict__ A,
                                                 const unsigned short* __restrict__ Bt,
                                                 float* __restrict__ C,
                                                 int M, int N, int K){
  __shared__ unsigned short As[64 * 32];
  __shared__ unsigned short Bs[128 * 32];
  const int tid = threadIdx.x;
  const int lane = tid & 63, w = tid >> 6;
  const int l15 = lane & 15, l4 = lane >> 4;

  const int chunk = gridDim.x >> 3;
  const int wgid = (blockIdx.x & 7) * chunk + (blockIdx.x >> 3);
  const int nm = M >> 6;
  const int bm = wgid % nm, bn = wgid / nm;
  const int m0 = bm * 64, n0 = bn * 128;

  const int r0 = tid >> 2;
  const int c0 = (tid & 3) << 3;

  const unsigned short* gA  = A  + (size_t)(m0 + r0) * K + c0;
  const unsigned short* gB0 = Bt + (size_t)(n0 + r0) * K + c0;
  const unsigned short* gB1 = Bt + (size_t)(n0 + 64 + r0) * K + c0;
  unsigned short* lA  = As + w * 512;
  unsigned short* lB0 = Bs + w * 512;
  unsigned short* lB1 = Bs + 2048 + w * 512;

  f32x4 acc[4][2] = {};

  for (int k0 = 0; k0 < K; k0 += 32){
    __syncthreads();
    gl16(gA  + k0, lA);
    gl16(gB0 + k0, lB0);
    gl16(gB1 + k0, lB1);
    __syncthreads();
    bf16x8 af[4], bfr[2];
    for (int i = 0; i < 4; i++)
      af[i] = *(const bf16x8*)&As[(i * 16 + l15) * 32 + l4 * 8];
    for (int j = 0; j < 2; j++)
      bfr[j] = *(const bf16x8*)&Bs[(w * 32 + j * 16 + l15) * 32 + l4 * 8];
    for (int i = 0; i < 4; i++)
      for (int j = 0; j < 2; j++)
        acc[i][j] = mfma16(af[i], bfr[j], acc[i][j]);
  }

  for (int i = 0; i < 4; i++)
    for (int j = 0; j < 2; j++){
      int col = n0 + w * 32 + j * 16 + l15;
      for (int r = 0; r < 4; r++){
        int row = m0 + i * 16 + l4 * 4 + r;
        size_t idx = (size_t)row * N + col;
        if (ADD) C[idx] += acc[i][j][r]; else C[idx] = acc[i][j][r];
      }
    }
}

// ================= 256x256 8-phase GEMM (T2+T3+T4+T5) =================
template<int EPI>
__global__ __launch_bounds__(512, 2) void gemm256(const unsigned short* __restrict__ A,
                                                  const unsigned short* __restrict__ Bt,
                                                  float* __restrict__ outF,
                                                  unsigned short* __restrict__ outH,
                                                  int M, int N, int K){
  __shared__ unsigned short lds[65536];  // 128 KiB
  const int tid = threadIdx.x;
  const int lane = tid & 63, w = tid >> 6;
  const int wm = w >> 2, wn = w & 3;
  const int l15 = lane & 15, l4 = lane >> 4;

  const int nwg = gridDim.x;
  const int xcd = (int)blockIdx.x & 7, lin = (int)blockIdx.x >> 3;
  const int q8 = nwg >> 3, r8 = nwg & 7;
  const int wgid = (xcd < r8 ? xcd * (q8 + 1) : r8 * (q8 + 1) + (xcd - r8) * q8) + lin;
  const int nm = M >> 8;
  const int bm = wgid % nm, bn = wgid / nm;
  const int m0 = bm * 256, n0 = bn * 256;
  const int NT = K >> 6;

  const int srow = (lane >> 3);
  const int scol = lane & 7;

  auto stageA = [&](int b, int h, int kt){
    #pragma unroll
    for (int c = 0; c < 2; c++){
      int r = w * 16 + c * 8 + srow;
      const unsigned short* g = A + (size_t)(m0 + h * 128 + r) * K + kt * 64 + ((scol ^ (r & 7)) << 3);
      gl16(g, (char*)lds + (b * 2 + h) * 16384 + (w * 16 + c * 8) * 128);
    }
  };
  auto stageB = [&](int b, int h, int kt){
    #pragma unroll
    for (int c = 0; c < 2; c++){
      int r = w * 16 + c * 8 + srow;
      const unsigned short* g = Bt + (size_t)(n0 + h * 128 + r) * K + kt * 64 + ((scol ^ (r & 7)) << 3);
      gl16(g, (char*)lds + 65536 + (b * 2 + h) * 16384 + (w * 16 + c * 8) * 128);
    }
  };

  const int sl0 = ((l4)     ^ (l15 & 7)) << 4;
  const int sl1 = ((4 | l4) ^ (l15 & 7)) << 4;

  f32x4 acc[8][4] = {};
  bf16x8 aF[8], bF[8];

  stageA(0, 0, 0); stageA(0, 1, 0); stageB(0, 0, 0); stageB(0, 1, 0);
  if (NT > 1){ stageB(1, 0, 1); stageB(1, 1, 1); }
  VMC4();
  SBAR();

  for (int kt = 0; kt < NT; kt++){
    const int buf = kt & 1;
    const char* Ab = (const char*)lds + (buf * 2 + wm) * 16384;
    const char* Bb = (const char*)lds + 65536 + (buf * 2 + (wn >> 1)) * 16384;
    const int brbase = (wn & 1) * 64;

    // PH1
    #pragma unroll
    for (int mf = 0; mf < 4; mf++){
      int r = mf * 16 + l15;
      aF[mf * 2 + 0] = *(const bf16x8*)(Ab + r * 128 + sl0);
      aF[mf * 2 + 1] = *(const bf16x8*)(Ab + r * 128 + sl1);
    }
    #pragma unroll
    for (int nf = 0; nf < 2; nf++){
      int r = brbase + nf * 16 + l15;
      bF[nf * 2 + 0] = *(const bf16x8*)(Bb + r * 128 + sl0);
      bF[nf * 2 + 1] = *(const bf16x8*)(Bb + r * 128 + sl1);
    }
    if (kt + 1 < NT) stageA(buf ^ 1, 0, kt + 1);
    SBAR(); LGK0();
    __builtin_amdgcn_s_setprio(1);
    #pragma unroll
    for (int mf = 0; mf < 4; mf++)
      #pragma unroll
      for (int nf = 0; nf < 2; nf++){
        acc[mf][nf] = mfma16(aF[mf * 2 + 0], bF[nf * 2 + 0], acc[mf][nf]);
        acc[mf][nf] = mfma16(aF[mf * 2 + 1], bF[nf * 2 + 1], acc[mf][nf]);
      }
    __builtin_amdgcn_s_setprio(0);
    SBAR();

    // PH2
    #pragma unroll
    for (int nf = 2; nf < 4; nf++){
      int r = brbase + nf * 16 + l15;
      bF[nf * 2 + 0] = *(const bf16x8*)(Bb + r * 128 + sl0);
      bF[nf * 2 + 1] = *(const bf16x8*)(Bb + r * 128 + sl1);
    }
    if (kt + 1 < NT) stageA(buf ^ 1, 1, kt + 1);
    SBAR(); LGK0();
    __builtin_amdgcn_s_setprio(1);
    #pragma unroll
    for (int mf = 0; mf < 4; mf++)
      #pragma unroll
      for (int nf = 2; nf < 4; nf++){
        acc[mf][nf] = mfma16(aF[mf * 2 + 0], bF[nf * 2 + 0], acc[mf][nf]);
        acc[mf][nf] = mfma16(aF[mf * 2 + 1], bF[nf * 2 + 1], acc[mf][nf]);
      }
    __builtin_amdgcn_s_setprio(0);
    SBAR();

    // PH3
    #pragma unroll
    for (int mf = 0; mf < 4; mf++){
      int r = 64 + mf * 16 + l15;
      aF[mf * 2 + 0] = *(const bf16x8*)(Ab + r * 128 + sl0);
      aF[mf * 2 + 1] = *(const bf16x8*)(Ab + r * 128 + sl1);
    }
    if (kt + 2 < NT) stageB(buf, 0, kt + 2);
    SBAR(); LGK0();
    __builtin_amdgcn_s_setprio(1);
    #pragma unroll
    for (int mf = 0; mf < 4; mf++)
      #pragma unroll
      for (int nf = 2; nf < 4; nf++){
        acc[4 + mf][nf] = mfma16(aF[mf * 2 + 0], bF[nf * 2 + 0], acc[4 + mf][nf]);
        acc[4 + mf][nf] = mfma16(aF[mf * 2 + 1], bF[nf * 2 + 1], acc[4 + mf][nf]);
      }
    __builtin_amdgcn_s_setprio(0);
    SBAR();

    // PH4
    if (kt + 2 < NT) stageB(buf, 1, kt + 2);
    SBAR();
    __builtin_amdgcn_s_setprio(1);
    #pragma unroll
    for (int mf = 0; mf < 4; mf++)
      #pragma unroll
      for (int nf = 0; nf < 2; nf++){
        acc[4 + mf][nf] = mfma16(aF[mf * 2 + 0], bF[nf * 2 + 0], acc[4 + mf][nf]);
        acc[4 + mf][nf] = mfma16(aF[mf * 2 + 1], bF[nf * 2 + 1], acc[4 + mf][nf]);
      }
    __builtin_amdgcn_s_setprio(0);
    if (kt + 2 < NT) { VMC4(); } else { VMC0(); }
    SBAR();
  }

  if (EPI == 0){
    #pragma unroll
    for (int mfg = 0; mfg < 8; mfg++){
      #pragma unroll
      for (int nf = 0; nf < 4; nf++){
        int col = n0 + wn * 64 + nf * 16 + l15;
        int row0 = m0 + wm * 128 + mfg * 16 + l4 * 4;
        #pragma unroll
        for (int r = 0; r < 4; r++)
          outF[(size_t)(row0 + r) * N + col] = acc[mfg][nf][r];
      }
    }
  } else {
    const int NH = N >> 1;
    #pragma unroll
    for (int mfg = 0; mfg < 8; mfg++){
      #pragma unroll
      for (int nfp = 0; nfp < 2; nfp++){
        int col = (n0 >> 1) + wn * 32 + nfp * 16 + l15;
        int row0 = m0 + wm * 128 + mfg * 16 + l4 * 4;
        #pragma unroll
        for (int r = 0; r < 4; r++){
          float u = acc[mfg][nfp * 2 + 0][r];
          float g = acc[mfg][nfp * 2 + 1][r];
          outH[(size_t)(row0 + r) * NH + col] = f2bf(u / (1.0f + __expf(-u)) * g);
        }
      }
    }
  }
}

// ---------------- q/k norm + rope + v transpose (Q pre-scaled by 0.125*log2e) ----------------
__global__ __launch_bounds__(256) void qkvpost_k(const float* __restrict__ qkv,
                                                 const float* __restrict__ qn,
                                                 const float* __restrict__ kn,
                                                 unsigned short* __restrict__ qb,
                                                 unsigned short* __restrict__ kb,
                                                 unsigned short* __restrict__ vt){
  const int t = blockIdx.x;
  const int lane = threadIdx.x & 63, w = threadIdx.x >> 6;
  const int d = lane;
  const int fi = d & 7;
  const float invf = powf(10000.0f, -(float)fi * 0.125f);
  const float ang = (float)t * invf;
  const float c = cosf(ang), s = sinf(ang);

  for (int i = 0; i < 4; i++){
    int h = w * 4 + i;
    float v = qkv[(size_t)t * 2560 + h * 128 + d];
    float ss = v * v;
    for (int m = 1; m < 64; m <<= 1) ss += __shfl_xor(ss, m);
    float r = rsqrtf(ss * (1.0f / D_H) + 1e-6f);
    float xn = v * r * (1.0f + qn[d]);
    float partner = __shfl_xor(xn, 8);
    float o;
    if (d < 8)       o = xn * c - partner * s;
    else if (d < 16) o = xn * c + partner * s;
    else             o = xn;
    qb[((size_t)h * T_LEN + t) * D_H + d] = f2bf(o * QSCALE);
  }
  {
    float v = qkv[(size_t)t * 2560 + 2048 + w * 64 + d];
    float ss = v * v;
    for (int m = 1; m < 64; m <<= 1) ss += __shfl_xor(ss, m);
    float r = rsqrtf(ss * (1.0f / D_H) + 1e-6f);
    float xn = v * r * (1.0f + kn[d]);
    float partner = __shfl_xor(xn, 8);
    float o;
    if (d < 8)       o = xn * c - partner * s;
    else if (d < 16) o = xn * c + partner * s;
    else             o = xn;
    kb[((size_t)w * T_LEN + t) * D_H + d] = f2bf(o);
  }
  {
    float v = qkv[(size_t)t * 2560 + 2304 + w * 64 + d];
    vt[((size_t)(w * 64 + d)) * T_LEN + t] = f2bf(v);
  }
}

// ---------------- flash attention: 4 waves/block, KV strided across waves, LDS merge ----------------
// Block (qt, h): 16 q-rows. Wave w handles KV chunks c = w, w+4, ... (64 wide each),
// with private online (m, l, O). One barrier; merge in LDS; gate+store.
// NOTE: no __syncthreads in the divergent chunk loop (waves have different trip counts).
__global__ __launch_bounds__(256) void attn_k(const unsigned short* __restrict__ qb,
                                              const unsigned short* __restrict__ kb,
                                              const unsigned short* __restrict__ vt,
                                              const float* __restrict__ qkv,
                                              unsigned short* __restrict__ ctxg){
  const int qt = blockIdx.x, h = blockIdx.y;
  const int g = h >> 2;
  const int tid = threadIdx.x;
  const int wv = tid >> 6;
  const int lane = tid & 63;
  const int l15 = lane & 15, l4 = lane >> 4;
  const int q0 = qt * 16;
  const int nch = (q0 >> 6) + 1;   // 64-wide chunks covering [0, q0+16)

  __shared__ unsigned short Pl[4][16][72];
  __shared__ float sO[4][16][66];
  __shared__ float sM[4][16];
  __shared__ float sL[4][16];

  const bf16x8 aq0 = *(const bf16x8*)(qb + ((size_t)h * T_LEN + q0 + l15) * D_H + l4 * 8);
  const bf16x8 aq1 = *(const bf16x8*)(qb + ((size_t)h * T_LEN + q0 + l15) * D_H + 32 + l4 * 8);

  f32x4 acc[4] = {};
  float mrun[4], lpart[4];
  #pragma unroll
  for (int j = 0; j < 4; j++){ mrun[j] = -1e30f; lpart[j] = 0.0f; }

  for (int c = wv; c < nch; c += 4){
    const int kv0 = c << 6;
    f32x4 sc[4];
    #pragma unroll
    for (int cp = 0; cp < 4; cp++){
      const unsigned short* kbase = kb + ((size_t)g * T_LEN + kv0 + cp * 16 + l15) * D_H + l4 * 8;
      bf16x8 bk0 = *(const bf16x8*)(kbase);
      bf16x8 bk1 = *(const bf16x8*)(kbase + 32);
      f32x4 z = {0.f, 0.f, 0.f, 0.f};
      z = mfma16(aq0, bk0, z);
      z = mfma16(aq1, bk1, z);
      sc[cp] = z;
    }
    float resc[4];
    #pragma unroll
    for (int j = 0; j < 4; j++){
      int r = q0 + l4 * 4 + j;
      #pragma unroll
      for (int cp = 0; cp < 4; cp++){
        int col = kv0 + cp * 16 + l15;
        sc[cp][j] = (col <= r) ? sc[cp][j] : -1e30f;
      }
      float mx = fmaxf(fmaxf(sc[0][j], sc[1][j]), fmaxf(sc[2][j], sc[3][j]));
      for (int off = 1; off < 16; off <<= 1) mx = fmaxf(mx, __shfl_xor(mx, off));
      float mnew = fmaxf(mrun[j], mx);
      resc[j] = exp2f(mrun[j] - mnew);
      mrun[j] = mnew;
      float ssum = 0.0f;
      #pragma unroll
      for (int cp = 0; cp < 4; cp++){
        float pv = exp2f(sc[cp][j] - mnew);
        sc[cp][j] = pv;
        ssum += pv;
      }
      lpart[j] = lpart[j] * resc[j] + ssum;
      #pragma unroll
      for (int nt = 0; nt < 4; nt++) acc[nt][j] *= resc[j];
    }
    // per-wave P staging (private slice; wave-internal ordering via lgkmcnt)
    #pragma unroll
    for (int j = 0; j < 4; j++)
      #pragma unroll
      for (int cp = 0; cp < 4; cp++)
        Pl[wv][l4 * 4 + j][cp * 16 + l15] = f2bf(sc[cp][j]);
    asm volatile("s_waitcnt lgkmcnt(0)" ::: "memory");
    const bf16x8 pa0 = *(const bf16x8*)&Pl[wv][l15][l4 * 8];
    const bf16x8 pa1 = *(const bf16x8*)&Pl[wv][l15][32 + l4 * 8];
    #pragma unroll
    for (int nt = 0; nt < 4; nt++){
      const unsigned short* vbase = vt + ((size_t)g * 64 + nt * 16 + l15) * T_LEN + kv0;
      bf16x8 bv0 = *(const bf16x8*)(vbase + l4 * 8);
      bf16x8 bv1 = *(const bf16x8*)(vbase + 32 + l4 * 8);
      acc[nt] = mfma16(pa1, bv1, mfma16(pa0, bv0, acc[nt]));
    }
  }

  // reduce l over the 16 lanes of the row group
  #pragma unroll
  for (int j = 0; j < 4; j++)
    for (int off = 1; off < 16; off <<= 1) lpart[j] += __shfl_xor(lpart[j], off);

  // publish partials
  #pragma unroll
  for (int j = 0; j < 4; j++){
    int row = l4 * 4 + j;
    #pragma unroll
    for (int nt = 0; nt < 4; nt++)
      sO[wv][row][nt * 16 + l15] = acc[nt][j];
  }
  if (l15 == 0){
    #pragma unroll
    for (int j = 0; j < 4; j++){
      sM[wv][l4 * 4 + j] = mrun[j];
      sL[wv][l4 * 4 + j] = lpart[j];
    }
  }
  __syncthreads();

  // merge: wave wv handles rows wv*4 .. wv*4+3; lane = d
  #pragma unroll
  for (int rr = 0; rr < 4; rr++){
    int r = wv * 4 + rr;
    float m0 = sM[0][r], m1 = sM[1][r], m2 = sM[2][r], m3 = sM[3][r];
    float ms = fmaxf(fmaxf(m0, m1), fmaxf(m2, m3));
    float w0 = exp2f(m0 - ms), w1 = exp2f(m1 - ms), w2 = exp2f(m2 - ms), w3 = exp2f(m3 - ms);
    float accv = w0 * sO[0][r][lane] + w1 * sO[1][r][lane] + w2 * sO[2][r][lane] + w3 * sO[3][r][lane];
    float lsum = w0 * sL[0][r] + w1 * sL[1][r] + w2 * sL[2][r] + w3 * sL[3][r];
    float gate = qkv[(size_t)(q0 + r) * 2560 + h * 128 + 64 + lane];
    float val = accv / lsum * (1.0f / (1.0f + __expf(-gate)));
    ctxg[(size_t)(q0 + r) * (H_N * D_H) + h * D_H + lane] = f2bf(val);
  }
}

extern "C" void kernel_launch(void* const* d_in, const int* in_sizes, int n_in,
                              void* d_out, int out_size, void* d_ws, size_t ws_size,
                              hipStream_t stream){
  (void)in_sizes; (void)n_in; (void)out_size; (void)ws_size;
  const int*   tokens = (const int*)d_in[0];
  const float* emb    = (const float*)d_in[1];
  const float* Wq     = (const float*)d_in[2];
  const float* Wk     = (const float*)d_in[3];
  const float* Wv     = (const float*)d_in[4];
  const float* Wo     = (const float*)d_in[5];
  const float* qn     = (const float*)d_in[6];
  const float* kn     = (const float*)d_in[7];
  const float* n1     = (const float*)d_in[8];
  const float* n2     = (const float*)d_in[9];
  const float* f1     = (const float*)d_in[10];
  const float* f2     = (const float*)d_in[11];
  const float* f3     = (const float*)d_in[12];
  const float* fn     = (const float*)d_in[13];
  const float* head   = (const float*)d_in[14];
  float* out = (float*)d_out;

  char* ws = (char*)d_ws;
  size_t off = 0;
  auto alloc = [&](size_t bytes)->char*{
    char* p = ws + off;
    off += (bytes + 255) & ~(size_t)255;
    return p;
  };
  float*          x       = (float*)alloc((size_t)T_LEN * E_DIM * 4);
  unsigned short* hbf     = (unsigned short*)alloc((size_t)T_LEN * E_DIM * 2);
  float*          qkvf    = (float*)alloc((size_t)T_LEN * 2560 * 4);
  unsigned short* qb      = (unsigned short*)alloc((size_t)H_N * T_LEN * D_H * 2);
  unsigned short* kb      = (unsigned short*)alloc((size_t)G_N * T_LEN * D_H * 2);
  unsigned short* vt      = (unsigned short*)alloc((size_t)G_N * D_H * T_LEN * 2);
  unsigned short* ctxg    = (unsigned short*)alloc((size_t)T_LEN * E_DIM * 2);
  unsigned short* hg      = (unsigned short*)alloc((size_t)T_LEN * F_DIM * 2);
  unsigned short* wt_qkv  = (unsigned short*)alloc((size_t)2560 * E_DIM * 2);
  unsigned short* wt_o    = (unsigned short*)alloc((size_t)E_DIM * E_DIM * 2);
  unsigned short* wt_f12i = (unsigned short*)alloc((size_t)2 * F_DIM * E_DIM * 2);
  unsigned short* wt_f3   = (unsigned short*)alloc((size_t)E_DIM * F_DIM * 2);
  unsigned short* wt_head = (unsigned short*)alloc((size_t)V_SZ * E_DIM * 2);

  embed_k<<<T_LEN, 256, 0, stream>>>(emb, tokens, x);
  transpose_bf16<<<dim3(V_SZ / 32, E_DIM / 32), 256, 0, stream>>>(head, wt_head, E_DIM, V_SZ);

  for (int l = 0; l < L_N; l++){
    prep_weights<<<15872, 256, 0, stream>>>(Wq + (size_t)l * E_DIM * 2048,
                                            Wk + (size_t)l * E_DIM * 256,
                                            Wv + (size_t)l * E_DIM * 256,
                                            Wo + (size_t)l * E_DIM * E_DIM,
                                            f1 + (size_t)l * E_DIM * F_DIM,
                                            f2 + (size_t)l * E_DIM * F_DIM,
                                            f3 + (size_t)l * F_DIM * E_DIM,
                                            wt_qkv, wt_o, wt_f12i, wt_f3);

    rmsnorm_k<<<T_LEN, 256, 0, stream>>>(x, n1 + l * E_DIM, hbf);
    gemm64_bt<false><<<(T_LEN / 64) * (2560 / 128), 256, 0, stream>>>(hbf, wt_qkv, qkvf, T_LEN, 2560, E_DIM);
    qkvpost_k<<<T_LEN, 256, 0, stream>>>(qkvf, qn + l * D_H, kn + l * D_H, qb, kb, vt);
    attn_k<<<dim3(T_LEN / 16, H_N), 256, 0, stream>>>(qb, kb, vt, qkvf, ctxg);
    gemm64_bt<true><<<(T_LEN / 64) * (E_DIM / 128), 256, 0, stream>>>(ctxg, wt_o, x, T_LEN, E_DIM, E_DIM);

    rmsnorm_k<<<T_LEN, 256, 0, stream>>>(x, n2 + l * E_DIM, hbf);
    gemm256<1><<<(T_LEN / 256) * (2 * F_DIM / 256), 512, 0, stream>>>(hbf, wt_f12i, nullptr, hg, T_LEN, 2 * F_DIM, E_DIM);
    gemm64_bt<true><<<(T_LEN / 64) * (E_DIM / 128), 256, 0, stream>>>(hg, wt_f3, x, T_LEN, E_DIM, F_DIM);
  }

  rmsnorm_k<<<T_LEN, 256, 0, stream>>>(x, fn, hbf);
  gemm256<0><<<(T_LEN / 256) * (V_SZ / 256), 512, 0, stream>>>(hbf, wt_head, out, nullptr, T_LEN, V_SZ, E_DIM);
}

// Round 9
// 1396.411 us; speedup vs baseline: 1.1771x; 1.0109x over previous
//
#include <hip/hip_runtime.h>

#define T_LEN 2048
#define E_DIM 1024
#define H_N 16
#define G_N 4
#define D_H 64
#define F_DIM 4096
#define V_SZ 32000
#define L_N 4

typedef __attribute__((ext_vector_type(8))) __bf16 bf16x8;
typedef __attribute__((ext_vector_type(4))) float f32x4;

__device__ __forceinline__ unsigned short f2bf(float f){
  unsigned int u = __float_as_uint(f);
  unsigned int r = (u + 0x7FFFu + ((u >> 16) & 1u)) >> 16;
  return (unsigned short)r;
}

__device__ __forceinline__ unsigned int packbf(float a, float b){
  return (unsigned int)f2bf(a) | ((unsigned int)f2bf(b) << 16);
}

__device__ __forceinline__ f32x4 mfma16(bf16x8 a, bf16x8 b, f32x4 c){
  return __builtin_amdgcn_mfma_f32_16x16x32_bf16(a, b, c, 0, 0, 0);
}

__device__ __forceinline__ void gl16(const void* g, void* l){
  __builtin_amdgcn_global_load_lds((const __attribute__((address_space(1))) void*)g,
                                   (__attribute__((address_space(3))) void*)l, 16, 0, 0);
}

#define SBAR() __builtin_amdgcn_s_barrier()
#define LGK0() do{ asm volatile("s_waitcnt lgkmcnt(0)" ::: "memory"); __builtin_amdgcn_sched_barrier(0); }while(0)
#define VMC4() do{ asm volatile("s_waitcnt vmcnt(4)" ::: "memory"); __builtin_amdgcn_sched_barrier(0); }while(0)
#define VMC0() do{ asm volatile("s_waitcnt vmcnt(0)" ::: "memory"); __builtin_amdgcn_sched_barrier(0); }while(0)

// 0.125 * log2(e): folded into Q so attention uses exp2 directly
#define QSCALE 0.1803368801111183f

// ---------------- embed gather ----------------
__global__ __launch_bounds__(256) void embed_k(const float* __restrict__ emb,
                                               const int* __restrict__ tokens,
                                               float* __restrict__ x){
  int t = blockIdx.x;
  int tok = tokens[t];
  const float4* src = (const float4*)(emb + (size_t)tok * E_DIM);
  float4* dst = (float4*)(x + (size_t)t * E_DIM);
  dst[threadIdx.x] = src[threadIdx.x];
}

// ---------------- transpose + fp32->bf16: dst[c][r] = src[r][c] (head only) ----------------
__global__ __launch_bounds__(256) void transpose_bf16(const float* __restrict__ src,
                                                      unsigned short* __restrict__ dst,
                                                      int R, int C){
  __shared__ float tile[32][33];
  int c0 = blockIdx.x * 32, r0 = blockIdx.y * 32;
  int tx = threadIdx.x & 31, ty = threadIdx.x >> 5;
  for (int i = 0; i < 4; i++){
    int r = ty + i * 8;
    tile[r][tx] = src[(size_t)(r0 + r) * C + c0 + tx];
  }
  __syncthreads();
  for (int i = 0; i < 4; i++){
    int r = ty + i * 8;
    dst[(size_t)(c0 + r) * R + r0 + tx] = f2bf(tile[tx][r]);
  }
}

// ---------------- per-layer weight prep: all transposes in ONE launch ----------------
__device__ __forceinline__ void tr32(const float* __restrict__ src, unsigned short* __restrict__ dst,
                                     int R, int C, int bx, int by, float* tile /*32x33*/){
  int c0 = bx * 32, r0 = by * 32;
  int tx = threadIdx.x & 31, ty = threadIdx.x >> 5;
  for (int i = 0; i < 4; i++){
    int r = ty + i * 8;
    tile[r * 33 + tx] = src[(size_t)(r0 + r) * C + c0 + tx];
  }
  __syncthreads();
  for (int i = 0; i < 4; i++){
    int r = ty + i * 8;
    dst[(size_t)(c0 + r) * R + r0 + tx] = f2bf(tile[tx * 33 + r]);
  }
}

// wt_f12i layout: row n' (0..8191): q=n'/32, r=n'%32; r<16 -> f1 col q*16+r ; r>=16 -> f2 col q*16+(r-16)
__global__ __launch_bounds__(256) void prep_weights(const float* __restrict__ Wq, const float* __restrict__ Wk,
                                                    const float* __restrict__ Wv, const float* __restrict__ Wo,
                                                    const float* __restrict__ f1, const float* __restrict__ f2,
                                                    const float* __restrict__ f3,
                                                    unsigned short* __restrict__ wt_qkv,
                                                    unsigned short* __restrict__ wt_o,
                                                    unsigned short* __restrict__ wt_f12i,
                                                    unsigned short* __restrict__ wt_f3){
  __shared__ float sh[1100];
  int id = blockIdx.x;
  if (id < 2048){ tr32(Wq, wt_qkv, 1024, 2048, id & 63, id >> 6, sh); return; }
  id -= 2048;
  if (id < 256){ tr32(Wk, wt_qkv + 2048 * 1024, 1024, 256, id & 7, id >> 3, sh); return; }
  id -= 256;
  if (id < 256){ tr32(Wv, wt_qkv + 2304 * 1024, 1024, 256, id & 7, id >> 3, sh); return; }
  id -= 256;
  if (id < 1024){ tr32(Wo, wt_o, 1024, 1024, id & 31, id >> 5, sh); return; }
  id -= 1024;
  if (id < 4096){ tr32(f3, wt_f3, 4096, 1024, id & 31, id >> 5, sh); return; }
  id -= 4096;
  {
    int q = id & 255, kb = id >> 8;
    float* t1 = sh; float* t2 = sh + 32 * 17;
    int c = threadIdx.x & 15, kk0 = threadIdx.x >> 4;
    for (int p = 0; p < 2; p++){
      int kk = p * 16 + kk0;
      t1[kk * 17 + c] = f1[(size_t)(kb * 32 + kk) * F_DIM + q * 16 + c];
      t2[kk * 17 + c] = f2[(size_t)(kb * 32 + kk) * F_DIM + q * 16 + c];
    }
    __syncthreads();
    int kk = threadIdx.x & 31, rb = threadIdx.x >> 5;
    for (int i = 0; i < 4; i++){
      int r = i * 8 + rb;
      float v = (r < 16) ? t1[kk * 17 + r] : t2[kk * 17 + (r - 16)];
      wt_f12i[(size_t)(q * 32 + r) * 1024 + kb * 32 + kk] = f2bf(v);
    }
  }
}

// ---------------- rmsnorm (row of 1024) fp32 -> bf16, out = n*(1+w) ----------------
__global__ __launch_bounds__(256) void rmsnorm_k(const float* __restrict__ x,
                                                 const float* __restrict__ w,
                                                 unsigned short* __restrict__ out){
  const int t = blockIdx.x, tid = threadIdx.x;
  const float4 v = ((const float4*)(x + (size_t)t * E_DIM))[tid];
  float ss = v.x*v.x + v.y*v.y + v.z*v.z + v.w*v.w;
  for (int m = 1; m < 64; m <<= 1) ss += __shfl_xor(ss, m);
  __shared__ float red[4];
  if ((tid & 63) == 0) red[tid >> 6] = ss;
  __syncthreads();
  ss = red[0] + red[1] + red[2] + red[3];
  const float r = rsqrtf(ss * (1.0f / E_DIM) + 1e-6f);
  const float4 wv = ((const float4*)w)[tid];
  ushort4 o;
  o.x = f2bf(v.x * r * (1.0f + wv.x));
  o.y = f2bf(v.y * r * (1.0f + wv.y));
  o.z = f2bf(v.z * r * (1.0f + wv.z));
  o.w = f2bf(v.w * r * (1.0f + wv.w));
  ((ushort4*)(out + (size_t)t * E_DIM))[tid] = o;
}

// ================= 64x128 GEMM (m97 structure, 256 thr) — small-N matmuls =================
template<bool ADD>
__global__ __launch_bounds__(256) void gemm64_bt(const unsigned short* __restrict__ A,
                                                 const unsigned short* __restrict__ Bt,
                                                 float* __restrict__ C,
                                                 int M, int N, int K){
  __shared__ unsigned short As[64 * 32];
  __shared__ unsigned short Bs[128 * 32];
  const int tid = threadIdx.x;
  const int lane = tid & 63, w = tid >> 6;
  const int l15 = lane & 15, l4 = lane >> 4;

  const int chunk = gridDim.x >> 3;
  const int wgid = (blockIdx.x & 7) * chunk + (blockIdx.x >> 3);
  const int nm = M >> 6;
  const int bm = wgid % nm, bn = wgid / nm;
  const int m0 = bm * 64, n0 = bn * 128;

  const int r0 = tid >> 2;
  const int c0 = (tid & 3) << 3;

  const unsigned short* gA  = A  + (size_t)(m0 + r0) * K + c0;
  const unsigned short* gB0 = Bt + (size_t)(n0 + r0) * K + c0;
  const unsigned short* gB1 = Bt + (size_t)(n0 + 64 + r0) * K + c0;
  unsigned short* lA  = As + w * 512;
  unsigned short* lB0 = Bs + w * 512;
  unsigned short* lB1 = Bs + 2048 + w * 512;

  f32x4 acc[4][2] = {};

  for (int k0 = 0; k0 < K; k0 += 32){
    __syncthreads();
    gl16(gA  + k0, lA);
    gl16(gB0 + k0, lB0);
    gl16(gB1 + k0, lB1);
    __syncthreads();
    bf16x8 af[4], bfr[2];
    for (int i = 0; i < 4; i++)
      af[i] = *(const bf16x8*)&As[(i * 16 + l15) * 32 + l4 * 8];
    for (int j = 0; j < 2; j++)
      bfr[j] = *(const bf16x8*)&Bs[(w * 32 + j * 16 + l15) * 32 + l4 * 8];
    for (int i = 0; i < 4; i++)
      for (int j = 0; j < 2; j++)
        acc[i][j] = mfma16(af[i], bfr[j], acc[i][j]);
  }

  for (int i = 0; i < 4; i++)
    for (int j = 0; j < 2; j++){
      int col = n0 + w * 32 + j * 16 + l15;
      for (int r = 0; r < 4; r++){
        int row = m0 + i * 16 + l4 * 4 + r;
        size_t idx = (size_t)row * N + col;
        if (ADD) C[idx] += acc[i][j][r]; else C[idx] = acc[i][j][r];
      }
    }
}

// ================= 256x256 8-phase GEMM (T2+T3+T4+T5) =================
template<int EPI>
__global__ __launch_bounds__(512, 2) void gemm256(const unsigned short* __restrict__ A,
                                                  const unsigned short* __restrict__ Bt,
                                                  float* __restrict__ outF,
                                                  unsigned short* __restrict__ outH,
                                                  int M, int N, int K){
  __shared__ unsigned short lds[65536];  // 128 KiB
  const int tid = threadIdx.x;
  const int lane = tid & 63, w = tid >> 6;
  const int wm = w >> 2, wn = w & 3;
  const int l15 = lane & 15, l4 = lane >> 4;

  const int nwg = gridDim.x;
  const int xcd = (int)blockIdx.x & 7, lin = (int)blockIdx.x >> 3;
  const int q8 = nwg >> 3, r8 = nwg & 7;
  const int wgid = (xcd < r8 ? xcd * (q8 + 1) : r8 * (q8 + 1) + (xcd - r8) * q8) + lin;
  const int nm = M >> 8;
  const int bm = wgid % nm, bn = wgid / nm;
  const int m0 = bm * 256, n0 = bn * 256;
  const int NT = K >> 6;

  const int srow = (lane >> 3);
  const int scol = lane & 7;

  auto stageA = [&](int b, int h, int kt){
    #pragma unroll
    for (int c = 0; c < 2; c++){
      int r = w * 16 + c * 8 + srow;
      const unsigned short* g = A + (size_t)(m0 + h * 128 + r) * K + kt * 64 + ((scol ^ (r & 7)) << 3);
      gl16(g, (char*)lds + (b * 2 + h) * 16384 + (w * 16 + c * 8) * 128);
    }
  };
  auto stageB = [&](int b, int h, int kt){
    #pragma unroll
    for (int c = 0; c < 2; c++){
      int r = w * 16 + c * 8 + srow;
      const unsigned short* g = Bt + (size_t)(n0 + h * 128 + r) * K + kt * 64 + ((scol ^ (r & 7)) << 3);
      gl16(g, (char*)lds + 65536 + (b * 2 + h) * 16384 + (w * 16 + c * 8) * 128);
    }
  };

  const int sl0 = ((l4)     ^ (l15 & 7)) << 4;
  const int sl1 = ((4 | l4) ^ (l15 & 7)) << 4;

  f32x4 acc[8][4] = {};
  bf16x8 aF[8], bF[8];

  stageA(0, 0, 0); stageA(0, 1, 0); stageB(0, 0, 0); stageB(0, 1, 0);
  if (NT > 1){ stageB(1, 0, 1); stageB(1, 1, 1); }
  VMC4();
  SBAR();

  for (int kt = 0; kt < NT; kt++){
    const int buf = kt & 1;
    const char* Ab = (const char*)lds + (buf * 2 + wm) * 16384;
    const char* Bb = (const char*)lds + 65536 + (buf * 2 + (wn >> 1)) * 16384;
    const int brbase = (wn & 1) * 64;

    // PH1
    #pragma unroll
    for (int mf = 0; mf < 4; mf++){
      int r = mf * 16 + l15;
      aF[mf * 2 + 0] = *(const bf16x8*)(Ab + r * 128 + sl0);
      aF[mf * 2 + 1] = *(const bf16x8*)(Ab + r * 128 + sl1);
    }
    #pragma unroll
    for (int nf = 0; nf < 2; nf++){
      int r = brbase + nf * 16 + l15;
      bF[nf * 2 + 0] = *(const bf16x8*)(Bb + r * 128 + sl0);
      bF[nf * 2 + 1] = *(const bf16x8*)(Bb + r * 128 + sl1);
    }
    if (kt + 1 < NT) stageA(buf ^ 1, 0, kt + 1);
    SBAR(); LGK0();
    __builtin_amdgcn_s_setprio(1);
    #pragma unroll
    for (int mf = 0; mf < 4; mf++)
      #pragma unroll
      for (int nf = 0; nf < 2; nf++){
        acc[mf][nf] = mfma16(aF[mf * 2 + 0], bF[nf * 2 + 0], acc[mf][nf]);
        acc[mf][nf] = mfma16(aF[mf * 2 + 1], bF[nf * 2 + 1], acc[mf][nf]);
      }
    __builtin_amdgcn_s_setprio(0);
    SBAR();

    // PH2
    #pragma unroll
    for (int nf = 2; nf < 4; nf++){
      int r = brbase + nf * 16 + l15;
      bF[nf * 2 + 0] = *(const bf16x8*)(Bb + r * 128 + sl0);
      bF[nf * 2 + 1] = *(const bf16x8*)(Bb + r * 128 + sl1);
    }
    if (kt + 1 < NT) stageA(buf ^ 1, 1, kt + 1);
    SBAR(); LGK0();
    __builtin_amdgcn_s_setprio(1);
    #pragma unroll
    for (int mf = 0; mf < 4; mf++)
      #pragma unroll
      for (int nf = 2; nf < 4; nf++){
        acc[mf][nf] = mfma16(aF[mf * 2 + 0], bF[nf * 2 + 0], acc[mf][nf]);
        acc[mf][nf] = mfma16(aF[mf * 2 + 1], bF[nf * 2 + 1], acc[mf][nf]);
      }
    __builtin_amdgcn_s_setprio(0);
    SBAR();

    // PH3
    #pragma unroll
    for (int mf = 0; mf < 4; mf++){
      int r = 64 + mf * 16 + l15;
      aF[mf * 2 + 0] = *(const bf16x8*)(Ab + r * 128 + sl0);
      aF[mf * 2 + 1] = *(const bf16x8*)(Ab + r * 128 + sl1);
    }
    if (kt + 2 < NT) stageB(buf, 0, kt + 2);
    SBAR(); LGK0();
    __builtin_amdgcn_s_setprio(1);
    #pragma unroll
    for (int mf = 0; mf < 4; mf++)
      #pragma unroll
      for (int nf = 2; nf < 4; nf++){
        acc[4 + mf][nf] = mfma16(aF[mf * 2 + 0], bF[nf * 2 + 0], acc[4 + mf][nf]);
        acc[4 + mf][nf] = mfma16(aF[mf * 2 + 1], bF[nf * 2 + 1], acc[4 + mf][nf]);
      }
    __builtin_amdgcn_s_setprio(0);
    SBAR();

    // PH4
    if (kt + 2 < NT) stageB(buf, 1, kt + 2);
    SBAR();
    __builtin_amdgcn_s_setprio(1);
    #pragma unroll
    for (int mf = 0; mf < 4; mf++)
      #pragma unroll
      for (int nf = 0; nf < 2; nf++){
        acc[4 + mf][nf] = mfma16(aF[mf * 2 + 0], bF[nf * 2 + 0], acc[4 + mf][nf]);
        acc[4 + mf][nf] = mfma16(aF[mf * 2 + 1], bF[nf * 2 + 1], acc[4 + mf][nf]);
      }
    __builtin_amdgcn_s_setprio(0);
    if (kt + 2 < NT) { VMC4(); } else { VMC0(); }
    SBAR();
  }

  if (EPI == 0){
    #pragma unroll
    for (int mfg = 0; mfg < 8; mfg++){
      #pragma unroll
      for (int nf = 0; nf < 4; nf++){
        int col = n0 + wn * 64 + nf * 16 + l15;
        int row0 = m0 + wm * 128 + mfg * 16 + l4 * 4;
        #pragma unroll
        for (int r = 0; r < 4; r++)
          outF[(size_t)(row0 + r) * N + col] = acc[mfg][nf][r];
      }
    }
  } else {
    const int NH = N >> 1;
    #pragma unroll
    for (int mfg = 0; mfg < 8; mfg++){
      #pragma unroll
      for (int nfp = 0; nfp < 2; nfp++){
        int col = (n0 >> 1) + wn * 32 + nfp * 16 + l15;
        int row0 = m0 + wm * 128 + mfg * 16 + l4 * 4;
        #pragma unroll
        for (int r = 0; r < 4; r++){
          float u = acc[mfg][nfp * 2 + 0][r];
          float g = acc[mfg][nfp * 2 + 1][r];
          outH[(size_t)(row0 + r) * NH + col] = f2bf(u / (1.0f + __expf(-u)) * g);
        }
      }
    }
  }
}

// ---------------- q/k norm + rope + v transpose (Q pre-scaled by 0.125*log2e) ----------------
__global__ __launch_bounds__(256) void qkvpost_k(const float* __restrict__ qkv,
                                                 const float* __restrict__ qn,
                                                 const float* __restrict__ kn,
                                                 unsigned short* __restrict__ qb,
                                                 unsigned short* __restrict__ kb,
                                                 unsigned short* __restrict__ vt){
  const int t = blockIdx.x;
  const int lane = threadIdx.x & 63, w = threadIdx.x >> 6;
  const int d = lane;
  const int fi = d & 7;
  const float invf = powf(10000.0f, -(float)fi * 0.125f);
  const float ang = (float)t * invf;
  const float c = cosf(ang), s = sinf(ang);

  for (int i = 0; i < 4; i++){
    int h = w * 4 + i;
    float v = qkv[(size_t)t * 2560 + h * 128 + d];
    float ss = v * v;
    for (int m = 1; m < 64; m <<= 1) ss += __shfl_xor(ss, m);
    float r = rsqrtf(ss * (1.0f / D_H) + 1e-6f);
    float xn = v * r * (1.0f + qn[d]);
    float partner = __shfl_xor(xn, 8);
    float o;
    if (d < 8)       o = xn * c - partner * s;
    else if (d < 16) o = xn * c + partner * s;
    else             o = xn;
    qb[((size_t)h * T_LEN + t) * D_H + d] = f2bf(o * QSCALE);
  }
  {
    float v = qkv[(size_t)t * 2560 + 2048 + w * 64 + d];
    float ss = v * v;
    for (int m = 1; m < 64; m <<= 1) ss += __shfl_xor(ss, m);
    float r = rsqrtf(ss * (1.0f / D_H) + 1e-6f);
    float xn = v * r * (1.0f + kn[d]);
    float partner = __shfl_xor(xn, 8);
    float o;
    if (d < 8)       o = xn * c - partner * s;
    else if (d < 16) o = xn * c + partner * s;
    else             o = xn;
    kb[((size_t)w * T_LEN + t) * D_H + d] = f2bf(o);
  }
  {
    float v = qkv[(size_t)t * 2560 + 2304 + w * 64 + d];
    vt[((size_t)(w * 64 + d)) * T_LEN + t] = f2bf(v);
  }
}

// ---------------- flash attention: 4 waves/block, KV strided across waves, LDS merge ----------------
// SWAPPED QK^T: z = mfma(K, Q) -> P[kv][q] with q = lane&15 -> per-lane scalar (m, l),
// in-lane row max/sum, packed b64 P staging, causal mask only on last chunk,
// exact defer-rescale when no lane's max grew (resc == 1).
__global__ __launch_bounds__(256) void attn_k(const unsigned short* __restrict__ qb,
                                              const unsigned short* __restrict__ kb,
                                              const unsigned short* __restrict__ vt,
                                              const float* __restrict__ qkv,
                                              unsigned short* __restrict__ ctxg){
  const int qt = blockIdx.x, h = blockIdx.y;
  const int g = h >> 2;
  const int tid = threadIdx.x;
  const int wv = tid >> 6;
  const int lane = tid & 63;
  const int l15 = lane & 15, l4 = lane >> 4;
  const int q0 = qt * 16;
  const int nch = (q0 >> 6) + 1;   // 64-wide chunks covering [0, q0+16)

  __shared__ unsigned short Pl[4][16][72];   // [wave][q-row][kv 0..63 + pad]; row = 144 B (16B-aligned)
  __shared__ float sO[4][16][66];
  __shared__ float sM[4][16];
  __shared__ float sL[4][16];

  const bf16x8 aq0 = *(const bf16x8*)(qb + ((size_t)h * T_LEN + q0 + l15) * D_H + l4 * 8);
  const bf16x8 aq1 = *(const bf16x8*)(qb + ((size_t)h * T_LEN + q0 + l15) * D_H + 32 + l4 * 8);

  f32x4 acc[4] = {};
  float m = -1e30f, lpart = 0.0f;

  for (int c = wv; c < nch; c += 4){
    const int kv0 = c << 6;
    f32x4 sc[4];
    #pragma unroll
    for (int cp = 0; cp < 4; cp++){
      const unsigned short* kbase = kb + ((size_t)g * T_LEN + kv0 + cp * 16 + l15) * D_H + l4 * 8;
      bf16x8 bk0 = *(const bf16x8*)(kbase);
      bf16x8 bk1 = *(const bf16x8*)(kbase + 32);
      f32x4 z = {0.f, 0.f, 0.f, 0.f};
      z = mfma16(bk0, aq0, z);         // swapped: D[kv][q], q = l15, kv = cp*16 + l4*4 + j
      z = mfma16(bk1, aq1, z);
      sc[cp] = z;
    }
    if (c == nch - 1){                 // only the last chunk can cross the causal diagonal
      #pragma unroll
      for (int cp = 0; cp < 4; cp++)
        #pragma unroll
        for (int j = 0; j < 4; j++){
          int kv = kv0 + cp * 16 + l4 * 4 + j;
          sc[cp][j] = (kv <= q0 + l15) ? sc[cp][j] : -1e30f;
        }
    }
    // in-lane max over 16 values + 2 cross-lane rounds (l4 group)
    float mx = sc[0][0];
    #pragma unroll
    for (int cp = 0; cp < 4; cp++)
      #pragma unroll
      for (int j = 0; j < 4; j++) mx = fmaxf(mx, sc[cp][j]);
    mx = fmaxf(mx, __shfl_xor(mx, 16));
    mx = fmaxf(mx, __shfl_xor(mx, 32));
    const float mnew = fmaxf(m, mx);
    const bool grew = !__all(mnew == m);
    const float mold = m;
    m = mnew;

    float ssum = 0.0f;
    unsigned int up[4][2];
    #pragma unroll
    for (int cp = 0; cp < 4; cp++){
      float p0 = exp2f(sc[cp][0] - mnew);
      float p1 = exp2f(sc[cp][1] - mnew);
      float p2 = exp2f(sc[cp][2] - mnew);
      float p3 = exp2f(sc[cp][3] - mnew);
      ssum += (p0 + p1) + (p2 + p3);
      up[cp][0] = packbf(p0, p1);
      up[cp][1] = packbf(p2, p3);
    }
    if (grew){
      const float resc = exp2f(mold - mnew);
      lpart *= resc;
      float r0 = __shfl(resc, l4 * 4 + 0);
      float r1 = __shfl(resc, l4 * 4 + 1);
      float r2 = __shfl(resc, l4 * 4 + 2);
      float r3 = __shfl(resc, l4 * 4 + 3);
      #pragma unroll
      for (int nt = 0; nt < 4; nt++){
        acc[nt][0] *= r0; acc[nt][1] *= r1; acc[nt][2] *= r2; acc[nt][3] *= r3;
      }
    }
    lpart += ssum;

    // packed P staging: 4 x ds_write_b64 -> Pl[wv][q=l15][kv]
    #pragma unroll
    for (int cp = 0; cp < 4; cp++){
      uint2 pr; pr.x = up[cp][0]; pr.y = up[cp][1];
      *(uint2*)&Pl[wv][l15][cp * 16 + l4 * 4] = pr;
    }
    asm volatile("s_waitcnt lgkmcnt(0)" ::: "memory");
    const bf16x8 pa0 = *(const bf16x8*)&Pl[wv][l15][l4 * 8];        // P[q=l15][kv 8*l4..+7]
    const bf16x8 pa1 = *(const bf16x8*)&Pl[wv][l15][32 + l4 * 8];
    #pragma unroll
    for (int nt = 0; nt < 4; nt++){
      const unsigned short* vbase = vt + ((size_t)g * 64 + nt * 16 + l15) * T_LEN + kv0;
      bf16x8 bv0 = *(const bf16x8*)(vbase + l4 * 8);
      bf16x8 bv1 = *(const bf16x8*)(vbase + 32 + l4 * 8);
      acc[nt] = mfma16(pa1, bv1, mfma16(pa0, bv0, acc[nt]));
    }
  }

  // finish l: sum the 4 per-lane partials of the l4 group
  lpart += __shfl_xor(lpart, 16);
  lpart += __shfl_xor(lpart, 32);

  // publish partials
  #pragma unroll
  for (int j = 0; j < 4; j++){
    int row = l4 * 4 + j;
    #pragma unroll
    for (int nt = 0; nt < 4; nt++)
      sO[wv][row][nt * 16 + l15] = acc[nt][j];
  }
  if (l4 == 0){
    sM[wv][l15] = m;
    sL[wv][l15] = lpart;
  }
  __syncthreads();

  // merge: wave wv handles rows wv*4 .. wv*4+3; lane = d
  #pragma unroll
  for (int rr = 0; rr < 4; rr++){
    int r = wv * 4 + rr;
    float m0 = sM[0][r], m1 = sM[1][r], m2 = sM[2][r], m3 = sM[3][r];
    float ms = fmaxf(fmaxf(m0, m1), fmaxf(m2, m3));
    float w0 = exp2f(m0 - ms), w1 = exp2f(m1 - ms), w2 = exp2f(m2 - ms), w3 = exp2f(m3 - ms);
    float accv = w0 * sO[0][r][lane] + w1 * sO[1][r][lane] + w2 * sO[2][r][lane] + w3 * sO[3][r][lane];
    float lsum = w0 * sL[0][r] + w1 * sL[1][r] + w2 * sL[2][r] + w3 * sL[3][r];
    float gate = qkv[(size_t)(q0 + r) * 2560 + h * 128 + 64 + lane];
    float val = accv / lsum * (1.0f / (1.0f + __expf(-gate)));
    ctxg[(size_t)(q0 + r) * (H_N * D_H) + h * D_H + lane] = f2bf(val);
  }
}

extern "C" void kernel_launch(void* const* d_in, const int* in_sizes, int n_in,
                              void* d_out, int out_size, void* d_ws, size_t ws_size,
                              hipStream_t stream){
  (void)in_sizes; (void)n_in; (void)out_size; (void)ws_size;
  const int*   tokens = (const int*)d_in[0];
  const float* emb    = (const float*)d_in[1];
  const float* Wq     = (const float*)d_in[2];
  const float* Wk     = (const float*)d_in[3];
  const float* Wv     = (const float*)d_in[4];
  const float* Wo     = (const float*)d_in[5];
  const float* qn     = (const float*)d_in[6];
  const float* kn     = (const float*)d_in[7];
  const float* n1     = (const float*)d_in[8];
  const float* n2     = (const float*)d_in[9];
  const float* f1     = (const float*)d_in[10];
  const float* f2     = (const float*)d_in[11];
  const float* f3     = (const float*)d_in[12];
  const float* fn     = (const float*)d_in[13];
  const float* head   = (const float*)d_in[14];
  float* out = (float*)d_out;

  char* ws = (char*)d_ws;
  size_t off = 0;
  auto alloc = [&](size_t bytes)->char*{
    char* p = ws + off;
    off += (bytes + 255) & ~(size_t)255;
    return p;
  };
  float*          x       = (float*)alloc((size_t)T_LEN * E_DIM * 4);
  unsigned short* hbf     = (unsigned short*)alloc((size_t)T_LEN * E_DIM * 2);
  float*          qkvf    = (float*)alloc((size_t)T_LEN * 2560 * 4);
  unsigned short* qb      = (unsigned short*)alloc((size_t)H_N * T_LEN * D_H * 2);
  unsigned short* kb      = (unsigned short*)alloc((size_t)G_N * T_LEN * D_H * 2);
  unsigned short* vt      = (unsigned short*)alloc((size_t)G_N * D_H * T_LEN * 2);
  unsigned short* ctxg    = (unsigned short*)alloc((size_t)T_LEN * E_DIM * 2);
  unsigned short* hg      = (unsigned short*)alloc((size_t)T_LEN * F_DIM * 2);
  unsigned short* wt_qkv  = (unsigned short*)alloc((size_t)2560 * E_DIM * 2);
  unsigned short* wt_o    = (unsigned short*)alloc((size_t)E_DIM * E_DIM * 2);
  unsigned short* wt_f12i = (unsigned short*)alloc((size_t)2 * F_DIM * E_DIM * 2);
  unsigned short* wt_f3   = (unsigned short*)alloc((size_t)E_DIM * F_DIM * 2);
  unsigned short* wt_head = (unsigned short*)alloc((size_t)V_SZ * E_DIM * 2);

  embed_k<<<T_LEN, 256, 0, stream>>>(emb, tokens, x);
  transpose_bf16<<<dim3(V_SZ / 32, E_DIM / 32), 256, 0, stream>>>(head, wt_head, E_DIM, V_SZ);

  for (int l = 0; l < L_N; l++){
    prep_weights<<<15872, 256, 0, stream>>>(Wq + (size_t)l * E_DIM * 2048,
                                            Wk + (size_t)l * E_DIM * 256,
                                            Wv + (size_t)l * E_DIM * 256,
                                            Wo + (size_t)l * E_DIM * E_DIM,
                                            f1 + (size_t)l * E_DIM * F_DIM,
                                            f2 + (size_t)l * E_DIM * F_DIM,
                                            f3 + (size_t)l * F_DIM * E_DIM,
                                            wt_qkv, wt_o, wt_f12i, wt_f3);

    rmsnorm_k<<<T_LEN, 256, 0, stream>>>(x, n1 + l * E_DIM, hbf);
    gemm64_bt<false><<<(T_LEN / 64) * (2560 / 128), 256, 0, stream>>>(hbf, wt_qkv, qkvf, T_LEN, 2560, E_DIM);
    qkvpost_k<<<T_LEN, 256, 0, stream>>>(qkvf, qn + l * D_H, kn + l * D_H, qb, kb, vt);
    attn_k<<<dim3(T_LEN / 16, H_N), 256, 0, stream>>>(qb, kb, vt, qkvf, ctxg);
    gemm64_bt<true><<<(T_LEN / 64) * (E_DIM / 128), 256, 0, stream>>>(ctxg, wt_o, x, T_LEN, E_DIM, E_DIM);

    rmsnorm_k<<<T_LEN, 256, 0, stream>>>(x, n2 + l * E_DIM, hbf);
    gemm256<1><<<(T_LEN / 256) * (2 * F_DIM / 256), 512, 0, stream>>>(hbf, wt_f12i, nullptr, hg, T_LEN, 2 * F_DIM, E_DIM);
    gemm64_bt<true><<<(T_LEN / 64) * (E_DIM / 128), 256, 0, stream>>>(hg, wt_f3, x, T_LEN, E_DIM, F_DIM);
  }

  rmsnorm_k<<<T_LEN, 256, 0, stream>>>(x, fn, hbf);
  gemm256<0><<<(T_LEN / 256) * (V_SZ / 256), 512, 0, stream>>>(hbf, wt_head, out, nullptr, T_LEN, V_SZ, E_DIM);
}

// Round 10
// 1385.716 us; speedup vs baseline: 1.1862x; 1.0077x over previous
//
#include <hip/hip_runtime.h>

#define T_LEN 2048
#define E_DIM 1024
#define H_N 16
#define G_N 4
#define D_H 64
#define F_DIM 4096
#define V_SZ 32000
#define L_N 4

typedef __attribute__((ext_vector_type(8))) __bf16 bf16x8;
typedef __attribute__((ext_vector_type(4))) float f32x4;

__device__ __forceinline__ unsigned short f2bf(float f){
  unsigned int u = __float_as_uint(f);
  unsigned int r = (u + 0x7FFFu + ((u >> 16) & 1u)) >> 16;
  return (unsigned short)r;
}

__device__ __forceinline__ unsigned int packbf(float a, float b){
  return (unsigned int)f2bf(a) | ((unsigned int)f2bf(b) << 16);
}

__device__ __forceinline__ f32x4 mfma16(bf16x8 a, bf16x8 b, f32x4 c){
  return __builtin_amdgcn_mfma_f32_16x16x32_bf16(a, b, c, 0, 0, 0);
}

__device__ __forceinline__ void gl16(const void* g, void* l){
  __builtin_amdgcn_global_load_lds((const __attribute__((address_space(1))) void*)g,
                                   (__attribute__((address_space(3))) void*)l, 16, 0, 0);
}

#define SBAR() __builtin_amdgcn_s_barrier()
#define LGK0() do{ asm volatile("s_waitcnt lgkmcnt(0)" ::: "memory"); __builtin_amdgcn_sched_barrier(0); }while(0)
#define VMC4() do{ asm volatile("s_waitcnt vmcnt(4)" ::: "memory"); __builtin_amdgcn_sched_barrier(0); }while(0)
#define VMC0() do{ asm volatile("s_waitcnt vmcnt(0)" ::: "memory"); __builtin_amdgcn_sched_barrier(0); }while(0)

// 0.125 * log2(e): folded into Q so attention uses exp2 directly
#define QSCALE 0.1803368801111183f

// ---------------- embed gather ----------------
__global__ __launch_bounds__(256) void embed_k(const float* __restrict__ emb,
                                               const int* __restrict__ tokens,
                                               float* __restrict__ x){
  int t = blockIdx.x;
  int tok = tokens[t];
  const float4* src = (const float4*)(emb + (size_t)tok * E_DIM);
  float4* dst = (float4*)(x + (size_t)t * E_DIM);
  dst[threadIdx.x] = src[threadIdx.x];
}

// ---------------- transpose + fp32->bf16: dst[c][r] = src[r][c] (head only) ----------------
__global__ __launch_bounds__(256) void transpose_bf16(const float* __restrict__ src,
                                                      unsigned short* __restrict__ dst,
                                                      int R, int C){
  __shared__ float tile[32][33];
  int c0 = blockIdx.x * 32, r0 = blockIdx.y * 32;
  int tx = threadIdx.x & 31, ty = threadIdx.x >> 5;
  for (int i = 0; i < 4; i++){
    int r = ty + i * 8;
    tile[r][tx] = src[(size_t)(r0 + r) * C + c0 + tx];
  }
  __syncthreads();
  for (int i = 0; i < 4; i++){
    int r = ty + i * 8;
    dst[(size_t)(c0 + r) * R + r0 + tx] = f2bf(tile[tx][r]);
  }
}

// ---------------- per-layer weight prep: all transposes in ONE launch ----------------
__device__ __forceinline__ void tr32(const float* __restrict__ src, unsigned short* __restrict__ dst,
                                     int R, int C, int bx, int by, float* tile /*32x33*/){
  int c0 = bx * 32, r0 = by * 32;
  int tx = threadIdx.x & 31, ty = threadIdx.x >> 5;
  for (int i = 0; i < 4; i++){
    int r = ty + i * 8;
    tile[r * 33 + tx] = src[(size_t)(r0 + r) * C + c0 + tx];
  }
  __syncthreads();
  for (int i = 0; i < 4; i++){
    int r = ty + i * 8;
    dst[(size_t)(c0 + r) * R + r0 + tx] = f2bf(tile[tx * 33 + r]);
  }
}

// wt_f12i layout: row n' (0..8191): q=n'/32, r=n'%32; r<16 -> f1 col q*16+r ; r>=16 -> f2 col q*16+(r-16)
__global__ __launch_bounds__(256) void prep_weights(const float* __restrict__ Wq, const float* __restrict__ Wk,
                                                    const float* __restrict__ Wv, const float* __restrict__ Wo,
                                                    const float* __restrict__ f1, const float* __restrict__ f2,
                                                    const float* __restrict__ f3,
                                                    unsigned short* __restrict__ wt_qkv,
                                                    unsigned short* __restrict__ wt_o,
                                                    unsigned short* __restrict__ wt_f12i,
                                                    unsigned short* __restrict__ wt_f3){
  __shared__ float sh[1100];
  int id = blockIdx.x;
  if (id < 2048){ tr32(Wq, wt_qkv, 1024, 2048, id & 63, id >> 6, sh); return; }
  id -= 2048;
  if (id < 256){ tr32(Wk, wt_qkv + 2048 * 1024, 1024, 256, id & 7, id >> 3, sh); return; }
  id -= 256;
  if (id < 256){ tr32(Wv, wt_qkv + 2304 * 1024, 1024, 256, id & 7, id >> 3, sh); return; }
  id -= 256;
  if (id < 1024){ tr32(Wo, wt_o, 1024, 1024, id & 31, id >> 5, sh); return; }
  id -= 1024;
  if (id < 4096){ tr32(f3, wt_f3, 4096, 1024, id & 31, id >> 5, sh); return; }
  id -= 4096;
  {
    int q = id & 255, kb = id >> 8;
    float* t1 = sh; float* t2 = sh + 32 * 17;
    int c = threadIdx.x & 15, kk0 = threadIdx.x >> 4;
    for (int p = 0; p < 2; p++){
      int kk = p * 16 + kk0;
      t1[kk * 17 + c] = f1[(size_t)(kb * 32 + kk) * F_DIM + q * 16 + c];
      t2[kk * 17 + c] = f2[(size_t)(kb * 32 + kk) * F_DIM + q * 16 + c];
    }
    __syncthreads();
    int kk = threadIdx.x & 31, rb = threadIdx.x >> 5;
    for (int i = 0; i < 4; i++){
      int r = i * 8 + rb;
      float v = (r < 16) ? t1[kk * 17 + r] : t2[kk * 17 + (r - 16)];
      wt_f12i[(size_t)(q * 32 + r) * 1024 + kb * 32 + kk] = f2bf(v);
    }
  }
}

// ---------------- rmsnorm (row of 1024) fp32 -> bf16, out = n*(1+w) ----------------
__global__ __launch_bounds__(256) void rmsnorm_k(const float* __restrict__ x,
                                                 const float* __restrict__ w,
                                                 unsigned short* __restrict__ out){
  const int t = blockIdx.x, tid = threadIdx.x;
  const float4 v = ((const float4*)(x + (size_t)t * E_DIM))[tid];
  float ss = v.x*v.x + v.y*v.y + v.z*v.z + v.w*v.w;
  for (int m = 1; m < 64; m <<= 1) ss += __shfl_xor(ss, m);
  __shared__ float red[4];
  if ((tid & 63) == 0) red[tid >> 6] = ss;
  __syncthreads();
  ss = red[0] + red[1] + red[2] + red[3];
  const float r = rsqrtf(ss * (1.0f / E_DIM) + 1e-6f);
  const float4 wv = ((const float4*)w)[tid];
  ushort4 o;
  o.x = f2bf(v.x * r * (1.0f + wv.x));
  o.y = f2bf(v.y * r * (1.0f + wv.y));
  o.z = f2bf(v.z * r * (1.0f + wv.z));
  o.w = f2bf(v.w * r * (1.0f + wv.w));
  ((ushort4*)(out + (size_t)t * E_DIM))[tid] = o;
}

// ================= 64x128 GEMM (m97 structure, 256 thr) — small-N matmuls =================
// MODE: 0 = write, 1 = non-atomic rmw add, 2 = atomicAdd (for split-K via blockIdx.y).
template<int MODE>
__global__ __launch_bounds__(256) void gemm64_bt(const unsigned short* __restrict__ A,
                                                 const unsigned short* __restrict__ Bt,
                                                 float* __restrict__ C,
                                                 int M, int N, int K){
  __shared__ unsigned short As[64 * 32];
  __shared__ unsigned short Bs[128 * 32];
  const int tid = threadIdx.x;
  const int lane = tid & 63, w = tid >> 6;
  const int l15 = lane & 15, l4 = lane >> 4;

  const int chunk = gridDim.x >> 3;
  const int wgid = (blockIdx.x & 7) * chunk + (blockIdx.x >> 3);
  const int nm = M >> 6;
  const int bm = wgid % nm, bn = wgid / nm;
  const int m0 = bm * 64, n0 = bn * 128;

  const int KS = K / gridDim.y;
  const int kbeg = blockIdx.y * KS;

  const int r0 = tid >> 2;
  const int c0 = (tid & 3) << 3;

  const unsigned short* gA  = A  + (size_t)(m0 + r0) * K + c0;
  const unsigned short* gB0 = Bt + (size_t)(n0 + r0) * K + c0;
  const unsigned short* gB1 = Bt + (size_t)(n0 + 64 + r0) * K + c0;
  unsigned short* lA  = As + w * 512;
  unsigned short* lB0 = Bs + w * 512;
  unsigned short* lB1 = Bs + 2048 + w * 512;

  f32x4 acc[4][2] = {};

  for (int k0 = kbeg; k0 < kbeg + KS; k0 += 32){
    __syncthreads();
    gl16(gA  + k0, lA);
    gl16(gB0 + k0, lB0);
    gl16(gB1 + k0, lB1);
    __syncthreads();
    bf16x8 af[4], bfr[2];
    for (int i = 0; i < 4; i++)
      af[i] = *(const bf16x8*)&As[(i * 16 + l15) * 32 + l4 * 8];
    for (int j = 0; j < 2; j++)
      bfr[j] = *(const bf16x8*)&Bs[(w * 32 + j * 16 + l15) * 32 + l4 * 8];
    for (int i = 0; i < 4; i++)
      for (int j = 0; j < 2; j++)
        acc[i][j] = mfma16(af[i], bfr[j], acc[i][j]);
  }

  for (int i = 0; i < 4; i++)
    for (int j = 0; j < 2; j++){
      int col = n0 + w * 32 + j * 16 + l15;
      for (int r = 0; r < 4; r++){
        int row = m0 + i * 16 + l4 * 4 + r;
        size_t idx = (size_t)row * N + col;
        if (MODE == 0) C[idx] = acc[i][j][r];
        else if (MODE == 1) C[idx] += acc[i][j][r];
        else atomicAdd(&C[idx], acc[i][j][r]);
      }
    }
}

// ================= 256x256 8-phase GEMM (T2+T3+T4+T5) =================
// EPI=0: fp32 store. EPI=1: f1/f2-interleaved silu-mul -> bf16 outH. EPI=2: atomicAdd fp32
// (split-K via blockIdx.y; each z-slice covers K/gridDim.y).
template<int EPI>
__global__ __launch_bounds__(512, 2) void gemm256(const unsigned short* __restrict__ A,
                                                  const unsigned short* __restrict__ Bt,
                                                  float* __restrict__ outF,
                                                  unsigned short* __restrict__ outH,
                                                  int M, int N, int K){
  __shared__ unsigned short lds[65536];  // 128 KiB
  const int tid = threadIdx.x;
  const int lane = tid & 63, w = tid >> 6;
  const int wm = w >> 2, wn = w & 3;
  const int l15 = lane & 15, l4 = lane >> 4;

  const int nwg = gridDim.x;
  const int xcd = (int)blockIdx.x & 7, lin = (int)blockIdx.x >> 3;
  const int q8 = nwg >> 3, r8 = nwg & 7;
  const int wgid = (xcd < r8 ? xcd * (q8 + 1) : r8 * (q8 + 1) + (xcd - r8) * q8) + lin;
  const int nm = M >> 8;
  const int bm = wgid % nm, bn = wgid / nm;
  const int m0 = bm * 256, n0 = bn * 256;

  const int KS = K / gridDim.y;
  const int kbeg = blockIdx.y * KS;
  const int NT = KS >> 6;

  const int srow = (lane >> 3);
  const int scol = lane & 7;

  auto stageA = [&](int b, int h, int kt){
    #pragma unroll
    for (int c = 0; c < 2; c++){
      int r = w * 16 + c * 8 + srow;
      const unsigned short* g = A + (size_t)(m0 + h * 128 + r) * K + kbeg + kt * 64 + ((scol ^ (r & 7)) << 3);
      gl16(g, (char*)lds + (b * 2 + h) * 16384 + (w * 16 + c * 8) * 128);
    }
  };
  auto stageB = [&](int b, int h, int kt){
    #pragma unroll
    for (int c = 0; c < 2; c++){
      int r = w * 16 + c * 8 + srow;
      const unsigned short* g = Bt + (size_t)(n0 + h * 128 + r) * K + kbeg + kt * 64 + ((scol ^ (r & 7)) << 3);
      gl16(g, (char*)lds + 65536 + (b * 2 + h) * 16384 + (w * 16 + c * 8) * 128);
    }
  };

  const int sl0 = ((l4)     ^ (l15 & 7)) << 4;
  const int sl1 = ((4 | l4) ^ (l15 & 7)) << 4;

  f32x4 acc[8][4] = {};
  bf16x8 aF[8], bF[8];

  stageA(0, 0, 0); stageA(0, 1, 0); stageB(0, 0, 0); stageB(0, 1, 0);
  if (NT > 1){ stageB(1, 0, 1); stageB(1, 1, 1); }
  VMC4();
  SBAR();

  for (int kt = 0; kt < NT; kt++){
    const int buf = kt & 1;
    const char* Ab = (const char*)lds + (buf * 2 + wm) * 16384;
    const char* Bb = (const char*)lds + 65536 + (buf * 2 + (wn >> 1)) * 16384;
    const int brbase = (wn & 1) * 64;

    // PH1
    #pragma unroll
    for (int mf = 0; mf < 4; mf++){
      int r = mf * 16 + l15;
      aF[mf * 2 + 0] = *(const bf16x8*)(Ab + r * 128 + sl0);
      aF[mf * 2 + 1] = *(const bf16x8*)(Ab + r * 128 + sl1);
    }
    #pragma unroll
    for (int nf = 0; nf < 2; nf++){
      int r = brbase + nf * 16 + l15;
      bF[nf * 2 + 0] = *(const bf16x8*)(Bb + r * 128 + sl0);
      bF[nf * 2 + 1] = *(const bf16x8*)(Bb + r * 128 + sl1);
    }
    if (kt + 1 < NT) stageA(buf ^ 1, 0, kt + 1);
    SBAR(); LGK0();
    __builtin_amdgcn_s_setprio(1);
    #pragma unroll
    for (int mf = 0; mf < 4; mf++)
      #pragma unroll
      for (int nf = 0; nf < 2; nf++){
        acc[mf][nf] = mfma16(aF[mf * 2 + 0], bF[nf * 2 + 0], acc[mf][nf]);
        acc[mf][nf] = mfma16(aF[mf * 2 + 1], bF[nf * 2 + 1], acc[mf][nf]);
      }
    __builtin_amdgcn_s_setprio(0);
    SBAR();

    // PH2
    #pragma unroll
    for (int nf = 2; nf < 4; nf++){
      int r = brbase + nf * 16 + l15;
      bF[nf * 2 + 0] = *(const bf16x8*)(Bb + r * 128 + sl0);
      bF[nf * 2 + 1] = *(const bf16x8*)(Bb + r * 128 + sl1);
    }
    if (kt + 1 < NT) stageA(buf ^ 1, 1, kt + 1);
    SBAR(); LGK0();
    __builtin_amdgcn_s_setprio(1);
    #pragma unroll
    for (int mf = 0; mf < 4; mf++)
      #pragma unroll
      for (int nf = 2; nf < 4; nf++){
        acc[mf][nf] = mfma16(aF[mf * 2 + 0], bF[nf * 2 + 0], acc[mf][nf]);
        acc[mf][nf] = mfma16(aF[mf * 2 + 1], bF[nf * 2 + 1], acc[mf][nf]);
      }
    __builtin_amdgcn_s_setprio(0);
    SBAR();

    // PH3
    #pragma unroll
    for (int mf = 0; mf < 4; mf++){
      int r = 64 + mf * 16 + l15;
      aF[mf * 2 + 0] = *(const bf16x8*)(Ab + r * 128 + sl0);
      aF[mf * 2 + 1] = *(const bf16x8*)(Ab + r * 128 + sl1);
    }
    if (kt + 2 < NT) stageB(buf, 0, kt + 2);
    SBAR(); LGK0();
    __builtin_amdgcn_s_setprio(1);
    #pragma unroll
    for (int mf = 0; mf < 4; mf++)
      #pragma unroll
      for (int nf = 2; nf < 4; nf++){
        acc[4 + mf][nf] = mfma16(aF[mf * 2 + 0], bF[nf * 2 + 0], acc[4 + mf][nf]);
        acc[4 + mf][nf] = mfma16(aF[mf * 2 + 1], bF[nf * 2 + 1], acc[4 + mf][nf]);
      }
    __builtin_amdgcn_s_setprio(0);
    SBAR();

    // PH4
    if (kt + 2 < NT) stageB(buf, 1, kt + 2);
    SBAR();
    __builtin_amdgcn_s_setprio(1);
    #pragma unroll
    for (int mf = 0; mf < 4; mf++)
      #pragma unroll
      for (int nf = 0; nf < 2; nf++){
        acc[4 + mf][nf] = mfma16(aF[mf * 2 + 0], bF[nf * 2 + 0], acc[4 + mf][nf]);
        acc[4 + mf][nf] = mfma16(aF[mf * 2 + 1], bF[nf * 2 + 1], acc[4 + mf][nf]);
      }
    __builtin_amdgcn_s_setprio(0);
    if (kt + 2 < NT) { VMC4(); } else { VMC0(); }
    SBAR();
  }

  if (EPI == 0 || EPI == 2){
    #pragma unroll
    for (int mfg = 0; mfg < 8; mfg++){
      #pragma unroll
      for (int nf = 0; nf < 4; nf++){
        int col = n0 + wn * 64 + nf * 16 + l15;
        int row0 = m0 + wm * 128 + mfg * 16 + l4 * 4;
        #pragma unroll
        for (int r = 0; r < 4; r++){
          size_t idx = (size_t)(row0 + r) * N + col;
          if (EPI == 0) outF[idx] = acc[mfg][nf][r];
          else atomicAdd(&outF[idx], acc[mfg][nf][r]);
        }
      }
    }
  } else {
    const int NH = N >> 1;
    #pragma unroll
    for (int mfg = 0; mfg < 8; mfg++){
      #pragma unroll
      for (int nfp = 0; nfp < 2; nfp++){
        int col = (n0 >> 1) + wn * 32 + nfp * 16 + l15;
        int row0 = m0 + wm * 128 + mfg * 16 + l4 * 4;
        #pragma unroll
        for (int r = 0; r < 4; r++){
          float u = acc[mfg][nfp * 2 + 0][r];
          float g = acc[mfg][nfp * 2 + 1][r];
          outH[(size_t)(row0 + r) * NH + col] = f2bf(u / (1.0f + __expf(-u)) * g);
        }
      }
    }
  }
}

// ---------------- q/k norm + rope + v transpose (Q pre-scaled by 0.125*log2e) ----------------
__global__ __launch_bounds__(256) void qkvpost_k(const float* __restrict__ qkv,
                                                 const float* __restrict__ qn,
                                                 const float* __restrict__ kn,
                                                 unsigned short* __restrict__ qb,
                                                 unsigned short* __restrict__ kb,
                                                 unsigned short* __restrict__ vt){
  const int t = blockIdx.x;
  const int lane = threadIdx.x & 63, w = threadIdx.x >> 6;
  const int d = lane;
  const int fi = d & 7;
  const float invf = powf(10000.0f, -(float)fi * 0.125f);
  const float ang = (float)t * invf;
  const float c = cosf(ang), s = sinf(ang);

  for (int i = 0; i < 4; i++){
    int h = w * 4 + i;
    float v = qkv[(size_t)t * 2560 + h * 128 + d];
    float ss = v * v;
    for (int m = 1; m < 64; m <<= 1) ss += __shfl_xor(ss, m);
    float r = rsqrtf(ss * (1.0f / D_H) + 1e-6f);
    float xn = v * r * (1.0f + qn[d]);
    float partner = __shfl_xor(xn, 8);
    float o;
    if (d < 8)       o = xn * c - partner * s;
    else if (d < 16) o = xn * c + partner * s;
    else             o = xn;
    qb[((size_t)h * T_LEN + t) * D_H + d] = f2bf(o * QSCALE);
  }
  {
    float v = qkv[(size_t)t * 2560 + 2048 + w * 64 + d];
    float ss = v * v;
    for (int m = 1; m < 64; m <<= 1) ss += __shfl_xor(ss, m);
    float r = rsqrtf(ss * (1.0f / D_H) + 1e-6f);
    float xn = v * r * (1.0f + kn[d]);
    float partner = __shfl_xor(xn, 8);
    float o;
    if (d < 8)       o = xn * c - partner * s;
    else if (d < 16) o = xn * c + partner * s;
    else             o = xn;
    kb[((size_t)w * T_LEN + t) * D_H + d] = f2bf(o);
  }
  {
    float v = qkv[(size_t)t * 2560 + 2304 + w * 64 + d];
    vt[((size_t)(w * 64 + d)) * T_LEN + t] = f2bf(v);
  }
}

// ---------------- flash attention: 4 waves/block, KV strided across waves, LDS merge ----------------
__global__ __launch_bounds__(256) void attn_k(const unsigned short* __restrict__ qb,
                                              const unsigned short* __restrict__ kb,
                                              const unsigned short* __restrict__ vt,
                                              const float* __restrict__ qkv,
                                              unsigned short* __restrict__ ctxg){
  const int qt = blockIdx.x, h = blockIdx.y;
  const int g = h >> 2;
  const int tid = threadIdx.x;
  const int wv = tid >> 6;
  const int lane = tid & 63;
  const int l15 = lane & 15, l4 = lane >> 4;
  const int q0 = qt * 16;
  const int nch = (q0 >> 6) + 1;

  __shared__ unsigned short Pl[4][16][72];
  __shared__ float sO[4][16][66];
  __shared__ float sM[4][16];
  __shared__ float sL[4][16];

  const bf16x8 aq0 = *(const bf16x8*)(qb + ((size_t)h * T_LEN + q0 + l15) * D_H + l4 * 8);
  const bf16x8 aq1 = *(const bf16x8*)(qb + ((size_t)h * T_LEN + q0 + l15) * D_H + 32 + l4 * 8);

  f32x4 acc[4] = {};
  float m = -1e30f, lpart = 0.0f;

  for (int c = wv; c < nch; c += 4){
    const int kv0 = c << 6;
    f32x4 sc[4];
    #pragma unroll
    for (int cp = 0; cp < 4; cp++){
      const unsigned short* kbase = kb + ((size_t)g * T_LEN + kv0 + cp * 16 + l15) * D_H + l4 * 8;
      bf16x8 bk0 = *(const bf16x8*)(kbase);
      bf16x8 bk1 = *(const bf16x8*)(kbase + 32);
      f32x4 z = {0.f, 0.f, 0.f, 0.f};
      z = mfma16(bk0, aq0, z);
      z = mfma16(bk1, aq1, z);
      sc[cp] = z;
    }
    if (c == nch - 1){
      #pragma unroll
      for (int cp = 0; cp < 4; cp++)
        #pragma unroll
        for (int j = 0; j < 4; j++){
          int kv = kv0 + cp * 16 + l4 * 4 + j;
          sc[cp][j] = (kv <= q0 + l15) ? sc[cp][j] : -1e30f;
        }
    }
    float mx = sc[0][0];
    #pragma unroll
    for (int cp = 0; cp < 4; cp++)
      #pragma unroll
      for (int j = 0; j < 4; j++) mx = fmaxf(mx, sc[cp][j]);
    mx = fmaxf(mx, __shfl_xor(mx, 16));
    mx = fmaxf(mx, __shfl_xor(mx, 32));
    const float mnew = fmaxf(m, mx);
    const bool grew = !__all(mnew == m);
    const float mold = m;
    m = mnew;

    float ssum = 0.0f;
    unsigned int up[4][2];
    #pragma unroll
    for (int cp = 0; cp < 4; cp++){
      float p0 = exp2f(sc[cp][0] - mnew);
      float p1 = exp2f(sc[cp][1] - mnew);
      float p2 = exp2f(sc[cp][2] - mnew);
      float p3 = exp2f(sc[cp][3] - mnew);
      ssum += (p0 + p1) + (p2 + p3);
      up[cp][0] = packbf(p0, p1);
      up[cp][1] = packbf(p2, p3);
    }
    if (grew){
      const float resc = exp2f(mold - mnew);
      lpart *= resc;
      float r0 = __shfl(resc, l4 * 4 + 0);
      float r1 = __shfl(resc, l4 * 4 + 1);
      float r2 = __shfl(resc, l4 * 4 + 2);
      float r3 = __shfl(resc, l4 * 4 + 3);
      #pragma unroll
      for (int nt = 0; nt < 4; nt++){
        acc[nt][0] *= r0; acc[nt][1] *= r1; acc[nt][2] *= r2; acc[nt][3] *= r3;
      }
    }
    lpart += ssum;

    #pragma unroll
    for (int cp = 0; cp < 4; cp++){
      uint2 pr; pr.x = up[cp][0]; pr.y = up[cp][1];
      *(uint2*)&Pl[wv][l15][cp * 16 + l4 * 4] = pr;
    }
    asm volatile("s_waitcnt lgkmcnt(0)" ::: "memory");
    const bf16x8 pa0 = *(const bf16x8*)&Pl[wv][l15][l4 * 8];
    const bf16x8 pa1 = *(const bf16x8*)&Pl[wv][l15][32 + l4 * 8];
    #pragma unroll
    for (int nt = 0; nt < 4; nt++){
      const unsigned short* vbase = vt + ((size_t)g * 64 + nt * 16 + l15) * T_LEN + kv0;
      bf16x8 bv0 = *(const bf16x8*)(vbase + l4 * 8);
      bf16x8 bv1 = *(const bf16x8*)(vbase + 32 + l4 * 8);
      acc[nt] = mfma16(pa1, bv1, mfma16(pa0, bv0, acc[nt]));
    }
  }

  lpart += __shfl_xor(lpart, 16);
  lpart += __shfl_xor(lpart, 32);

  #pragma unroll
  for (int j = 0; j < 4; j++){
    int row = l4 * 4 + j;
    #pragma unroll
    for (int nt = 0; nt < 4; nt++)
      sO[wv][row][nt * 16 + l15] = acc[nt][j];
  }
  if (l4 == 0){
    sM[wv][l15] = m;
    sL[wv][l15] = lpart;
  }
  __syncthreads();

  #pragma unroll
  for (int rr = 0; rr < 4; rr++){
    int r = wv * 4 + rr;
    float m0 = sM[0][r], m1 = sM[1][r], m2 = sM[2][r], m3 = sM[3][r];
    float ms = fmaxf(fmaxf(m0, m1), fmaxf(m2, m3));
    float w0 = exp2f(m0 - ms), w1 = exp2f(m1 - ms), w2 = exp2f(m2 - ms), w3 = exp2f(m3 - ms);
    float accv = w0 * sO[0][r][lane] + w1 * sO[1][r][lane] + w2 * sO[2][r][lane] + w3 * sO[3][r][lane];
    float lsum = w0 * sL[0][r] + w1 * sL[1][r] + w2 * sL[2][r] + w3 * sL[3][r];
    float gate = qkv[(size_t)(q0 + r) * 2560 + h * 128 + 64 + lane];
    float val = accv / lsum * (1.0f / (1.0f + __expf(-gate)));
    ctxg[(size_t)(q0 + r) * (H_N * D_H) + h * D_H + lane] = f2bf(val);
  }
}

extern "C" void kernel_launch(void* const* d_in, const int* in_sizes, int n_in,
                              void* d_out, int out_size, void* d_ws, size_t ws_size,
                              hipStream_t stream){
  (void)in_sizes; (void)n_in; (void)out_size; (void)ws_size;
  const int*   tokens = (const int*)d_in[0];
  const float* emb    = (const float*)d_in[1];
  const float* Wq     = (const float*)d_in[2];
  const float* Wk     = (const float*)d_in[3];
  const float* Wv     = (const float*)d_in[4];
  const float* Wo     = (const float*)d_in[5];
  const float* qn     = (const float*)d_in[6];
  const float* kn     = (const float*)d_in[7];
  const float* n1     = (const float*)d_in[8];
  const float* n2     = (const float*)d_in[9];
  const float* f1     = (const float*)d_in[10];
  const float* f2     = (const float*)d_in[11];
  const float* f3     = (const float*)d_in[12];
  const float* fn     = (const float*)d_in[13];
  const float* head   = (const float*)d_in[14];
  float* out = (float*)d_out;

  char* ws = (char*)d_ws;
  size_t off = 0;
  auto alloc = [&](size_t bytes)->char*{
    char* p = ws + off;
    off += (bytes + 255) & ~(size_t)255;
    return p;
  };
  float*          x       = (float*)alloc((size_t)T_LEN * E_DIM * 4);
  unsigned short* hbf     = (unsigned short*)alloc((size_t)T_LEN * E_DIM * 2);
  float*          qkvf    = (float*)alloc((size_t)T_LEN * 2560 * 4);
  unsigned short* qb      = (unsigned short*)alloc((size_t)H_N * T_LEN * D_H * 2);
  unsigned short* kb      = (unsigned short*)alloc((size_t)G_N * T_LEN * D_H * 2);
  unsigned short* vt      = (unsigned short*)alloc((size_t)G_N * D_H * T_LEN * 2);
  unsigned short* ctxg    = (unsigned short*)alloc((size_t)T_LEN * E_DIM * 2);
  unsigned short* hg      = (unsigned short*)alloc((size_t)T_LEN * F_DIM * 2);
  unsigned short* wt_qkv  = (unsigned short*)alloc((size_t)2560 * E_DIM * 2);
  unsigned short* wt_o    = (unsigned short*)alloc((size_t)E_DIM * E_DIM * 2);
  unsigned short* wt_f12i = (unsigned short*)alloc((size_t)2 * F_DIM * E_DIM * 2);
  unsigned short* wt_f3   = (unsigned short*)alloc((size_t)E_DIM * F_DIM * 2);
  unsigned short* wt_head = (unsigned short*)alloc((size_t)V_SZ * E_DIM * 2);

  embed_k<<<T_LEN, 256, 0, stream>>>(emb, tokens, x);
  transpose_bf16<<<dim3(V_SZ / 32, E_DIM / 32), 256, 0, stream>>>(head, wt_head, E_DIM, V_SZ);

  for (int l = 0; l < L_N; l++){
    prep_weights<<<15872, 256, 0, stream>>>(Wq + (size_t)l * E_DIM * 2048,
                                            Wk + (size_t)l * E_DIM * 256,
                                            Wv + (size_t)l * E_DIM * 256,
                                            Wo + (size_t)l * E_DIM * E_DIM,
                                            f1 + (size_t)l * E_DIM * F_DIM,
                                            f2 + (size_t)l * E_DIM * F_DIM,
                                            f3 + (size_t)l * F_DIM * E_DIM,
                                            wt_qkv, wt_o, wt_f12i, wt_f3);

    rmsnorm_k<<<T_LEN, 256, 0, stream>>>(x, n1 + l * E_DIM, hbf);
    gemm64_bt<0><<<(T_LEN / 64) * (2560 / 128), 256, 0, stream>>>(hbf, wt_qkv, qkvf, T_LEN, 2560, E_DIM);
    qkvpost_k<<<T_LEN, 256, 0, stream>>>(qkvf, qn + l * D_H, kn + l * D_H, qb, kb, vt);
    attn_k<<<dim3(T_LEN / 16, H_N), 256, 0, stream>>>(qb, kb, vt, qkvf, ctxg);
    gemm64_bt<2><<<dim3((T_LEN / 64) * (E_DIM / 128), 2), 256, 0, stream>>>(ctxg, wt_o, x, T_LEN, E_DIM, E_DIM);

    rmsnorm_k<<<T_LEN, 256, 0, stream>>>(x, n2 + l * E_DIM, hbf);
    gemm256<1><<<(T_LEN / 256) * (2 * F_DIM / 256), 512, 0, stream>>>(hbf, wt_f12i, nullptr, hg, T_LEN, 2 * F_DIM, E_DIM);
    gemm256<2><<<dim3((T_LEN / 256) * (E_DIM / 256), 8), 512, 0, stream>>>(hg, wt_f3, x, nullptr, T_LEN, E_DIM, F_DIM);
  }

  rmsnorm_k<<<T_LEN, 256, 0, stream>>>(x, fn, hbf);
  gemm256<0><<<(T_LEN / 256) * (V_SZ / 256), 512, 0, stream>>>(hbf, wt_head, out, nullptr, T_LEN, V_SZ, E_DIM);
}